// Round 5
// baseline (769.323 us; speedup 1.0000x reference)
//
#include <hip/hip_runtime.h>
#include <cstdint>

// ---------------------------------------------------------------------------
// GatedCrossAttention  (E=1024, Z=256, L=2048, B=8)
// Round 5: 256^2 8-phase engine = round-4 schedule (one vmcnt(6)/K-tile,
// 4-phase zigzag, setprio, XCD swizzle) + round-1 CONSUMPTION-DEFINED
// staging halves (A: bit6, B: bit5) — fixes round 4's overwrite hazard.
// k-GEMM (N=256) stays on the 128^2 engine.
// ---------------------------------------------------------------------------

#define EN 1024
#define ZN 256
#define LN_ 2048
#define BN_ 8
#define MROWS (LN_ * BN_)          // 16384
#define QRU_N (2 * EN + ZN)        // 2304
#define LEN_SCALE 0.022097086912079608f  // 1/sqrt(2048)

typedef unsigned short u16;
typedef __bf16 bf16x8 __attribute__((ext_vector_type(8)));
typedef float f32x4 __attribute__((ext_vector_type(4)));

// ---- bf16 helpers ---------------------------------------------------------
__device__ __forceinline__ u16 f2bf(float f) {
    unsigned int u = __float_as_uint(f);
    u = (u + 0x7fff + ((u >> 16) & 1)) >> 16;
    return (u16)u;
}
__device__ __forceinline__ float bf2f(u16 s) {
    return __uint_as_float(((unsigned int)s) << 16);
}
__device__ __forceinline__ void store_bf16x4(u16* p, float a, float b, float c, float d) {
    union { u16 h[4]; uint2 v; } pk;
    pk.h[0] = f2bf(a); pk.h[1] = f2bf(b); pk.h[2] = f2bf(c); pk.h[3] = f2bf(d);
    *(uint2*)p = pk.v;
}

// ---- async global->LDS (16B/lane, wave-uniform LDS base + lane*16) --------
__device__ __forceinline__ void async_load16(const void* g, void* l) {
    __builtin_amdgcn_global_load_lds(
        (const __attribute__((address_space(1))) void*)g,
        (__attribute__((address_space(3))) void*)l,
        16, 0, 0);
}

#define GB_BAR()  asm volatile("s_barrier" ::: "memory")
#define GB_VMC(n) asm volatile("s_waitcnt vmcnt(" #n ")" ::: "memory")

// ===========================================================================
// 256x256 8-phase engine.  C = A[M,K] @ B[N,K]^T.
//
// LDS: 2 buffers x (A[256][64] + B[256][64]) bf16 = 128 KiB.  Rows are 64
// elems (128 B, 8x 16B chunks); chunk c of row r stored at c ^ (r&7)
// (pre-swizzled global source col of global_load_lds; undone on read).
//
// 8 waves, 2M x 4N; wave output 128x64 = acc[8][4] f32x4.
// CONSUMPTION-DEFINED half-tiles (must match rd_a/rd_b row sets!):
//   A-half h = rows with bit6==h: {h*64+0..63, 128+h*64+0..63}
//   B-half h = rows with bit5==h: {g*64+h*32+0..31, g=0..3}
// Per K-tile t (buf t&1), 4 phases in zigzag quadrant order:
//   p0 (M0,N0): ds_read A0(8)+B0(4); stage (t+1).B0 -> buf[t+1]
//   p1 (M0,N1): ds_read B1(4)      ; stage (t+2).A0 -> buf[t]  (A0 dead @p0)
//   p2 (M1,N1): ds_read A1(8)      ; stage (t+2).B1 -> buf[t]  (B1 dead @p1)
//   p3 (M1,N0): ds_read B0(4)      ; stage (t+2).A1 -> buf[t]  (A1 dead @p2)
// Each phase: {reads; stage; s_barrier; MFMA x16 (setprio 1); s_barrier}.
// ONE wait per tile, after p3's MFMA: vmcnt(6).  FIFO invariant (verified):
// entering tile t, outstanding = (t+1).{A0,B1,A1} (6 loads); end-of-t
// vmcnt(6) retires those + p0's (t+1).B0 = tile t+1 fully landed.
// Tail: t==NT-2 -> vmcnt(0); t==NT-1 -> no stage/wait.  Requires NT>=2,
// M%256==0, N%256==0, K%64==0, gridDim.x*gridDim.y % 8 == 0.
// ===========================================================================
template <int MH>
__device__ __forceinline__ void rd_a(const u16* __restrict__ s, int wm, int l16, int quad,
                                     bf16x8 (&af)[4][2]) {
#pragma unroll
    for (int mi = 0; mi < 4; ++mi)
#pragma unroll
        for (int ks = 0; ks < 2; ++ks)
            af[mi][ks] = *(const bf16x8*)&s[(wm * 128 + MH * 64 + mi * 16 + l16) * 64 +
                                            (((ks * 4 + quad) ^ (l16 & 7)) * 8)];
}
template <int NH>
__device__ __forceinline__ void rd_b(const u16* __restrict__ s, int wn, int l16, int quad,
                                     bf16x8 (&bv)[2][2]) {
#pragma unroll
    for (int ni = 0; ni < 2; ++ni)
#pragma unroll
        for (int ks = 0; ks < 2; ++ks)
            bv[ni][ks] = *(const bf16x8*)&s[(wn * 64 + NH * 32 + ni * 16 + l16) * 64 +
                                            (((ks * 4 + quad) ^ (l16 & 7)) * 8)];
}
template <int MH, int NH>
__device__ __forceinline__ void quad_mfma(const bf16x8 (&af)[4][2], const bf16x8 (&bv)[2][2],
                                          f32x4 (&acc)[8][4]) {
    __builtin_amdgcn_s_setprio(1);
#pragma unroll
    for (int mi = 0; mi < 4; ++mi)
#pragma unroll
        for (int ni = 0; ni < 2; ++ni)
#pragma unroll
            for (int ks = 0; ks < 2; ++ks)
                acc[MH * 4 + mi][NH * 2 + ni] = __builtin_amdgcn_mfma_f32_16x16x32_bf16(
                    af[mi][ks], bv[ni][ks], acc[MH * 4 + mi][NH * 2 + ni], 0, 0, 0);
    __builtin_amdgcn_s_setprio(0);
}

template <typename Epi>
__global__ __launch_bounds__(512, 2)
void gemm256(const u16* __restrict__ A, const u16* __restrict__ B,
             long long batchStrideA, long long batchStrideB, int K, Epi epi)
{
    __shared__ __align__(16) u16 As[2][256 * 64];
    __shared__ __align__(16) u16 Bs[2][256 * 64];

    const int tid  = threadIdx.x;
    const int lane = tid & 63;
    const int w    = tid >> 6;            // 0..7
    const int wm   = w >> 2, wn = w & 3;  // 2x4 wave grid
    const int quad = lane >> 4, l16 = lane & 15;
    const int bz   = blockIdx.z;

    // T1: XCD-aware swizzle (bijective; all grids here have nwg % 8 == 0)
    const int gx   = gridDim.x;
    const int nwg  = gx * gridDim.y;
    const int orig = blockIdx.y * gx + blockIdx.x;
    const int swz  = ((nwg & 7) == 0) ? ((orig & 7) * (nwg >> 3) + (orig >> 3)) : orig;
    const long long m0 = (long long)(swz / gx) * 256;
    const long long n0 = (long long)(swz % gx) * 256;

    const u16* Ab = A + bz * batchStrideA;
    const u16* Bb = B + bz * batchStrideB;

    // staging geometry: each instr covers 8 rows; lane l -> row +(l>>3),
    // dest chunk l&7; swizzled source col chunk = (l&7)^(l>>3)
    const int srow = lane >> 3;
    const int scol = ((lane & 7) ^ srow) * 8;

    // consumption-defined staging row bases (verified correct in round 1)
    int rA_[2][2], rB_[2][2];
#pragma unroll
    for (int h = 0; h < 2; ++h)
#pragma unroll
        for (int j = 0; j < 2; ++j) {
            const int gg = w * 2 + j;     // 0..15, wave-uniform
            rA_[h][j] = (gg < 8) ? (h * 64 + gg * 8) : (128 + h * 64 + (gg - 8) * 8);
            rB_[h][j] = (gg >> 2) * 64 + h * 32 + (gg & 3) * 8;
        }
    const u16* pA_[2][2]; const u16* pB_[2][2];
#pragma unroll
    for (int h = 0; h < 2; ++h)
#pragma unroll
        for (int j = 0; j < 2; ++j) {
            pA_[h][j] = Ab + (m0 + rA_[h][j] + srow) * K + scol;
            pB_[h][j] = Bb + (n0 + rB_[h][j] + srow) * K + scol;
        }

    auto stageA = [&](int buf, int h, long long ko) {
        async_load16(pA_[h][0] + ko, (void*)&As[buf][rA_[h][0] * 64]);
        async_load16(pA_[h][1] + ko, (void*)&As[buf][rA_[h][1] * 64]);
    };
    auto stageB = [&](int buf, int h, long long ko) {
        async_load16(pB_[h][0] + ko, (void*)&Bs[buf][rB_[h][0] * 64]);
        async_load16(pB_[h][1] + ko, (void*)&Bs[buf][rB_[h][1] * 64]);
    };

    const f32x4 fz = {0.f, 0.f, 0.f, 0.f};
    f32x4 acc[8][4];
#pragma unroll
    for (int i = 0; i < 8; ++i)
#pragma unroll
        for (int j = 0; j < 4; ++j) acc[i][j] = fz;

    bf16x8 af[4][2], bv[2][2];
    const int NT = K >> 6;

    // ---- prologue: tile0 {A0,B0,B1,A1}; tile1 {A0,B1,A1}; vmcnt(6) ----
    stageA(0, 0, 0); stageB(0, 0, 0); stageB(0, 1, 0); stageA(0, 1, 0);
    if (NT > 1) { stageA(1, 0, 64); stageB(1, 1, 64); stageA(1, 1, 64); }
    if (NT > 1) { GB_VMC(6); } else { GB_VMC(0); }   // tile0 fully landed
    GB_BAR();

    for (int t = 0; t < NT; ++t) {
        const u16* Ac = As[t & 1];
        const u16* Bc = Bs[t & 1];
        const int  nb = (t + 1) & 1;
        const long long k1 = (long long)(t + 1) << 6;
        const long long k2 = (long long)(t + 2) << 6;
        const bool s1 = (t + 1 < NT), s2 = (t + 2 < NT);

        // ---- p0: (M0,N0) ----
        rd_a<0>(Ac, wm, l16, quad, af);
        rd_b<0>(Bc, wn, l16, quad, bv);
        if (s1) stageB(nb, 0, k1);
        GB_BAR();
        quad_mfma<0, 0>(af, bv, acc);
        GB_BAR();
        // ---- p1: (M0,N1) ----
        rd_b<1>(Bc, wn, l16, quad, bv);
        if (s2) stageA(t & 1, 0, k2);
        GB_BAR();
        quad_mfma<0, 1>(af, bv, acc);
        GB_BAR();
        // ---- p2: (M1,N1) ----
        rd_a<1>(Ac, wm, l16, quad, af);
        if (s2) stageB(t & 1, 1, k2);
        GB_BAR();
        quad_mfma<1, 1>(af, bv, acc);
        GB_BAR();
        // ---- p3: (M1,N0) ----
        rd_b<0>(Bc, wn, l16, quad, bv);
        if (s2) stageA(t & 1, 1, k2);
        GB_BAR();
        quad_mfma<1, 0>(af, bv, acc);
        if (t < NT - 2)       { GB_VMC(6); }   // tile t+1 fully landed
        else if (t == NT - 2) { GB_VMC(0); }
        GB_BAR();
    }

    // epilogue: D[row][col], col = lane&15, row = quad*4 + reg  [m89/m91]
#pragma unroll
    for (int mi = 0; mi < 8; ++mi)
#pragma unroll
        for (int ni = 0; ni < 4; ++ni)
#pragma unroll
            for (int r = 0; r < 4; ++r) {
                int m = (int)m0 + wm * 128 + mi * 16 + quad * 4 + r;
                int n = (int)n0 + wn * 64 + ni * 16 + l16;
                epi(bz, m, n, acc[mi][ni][r]);
            }
}

// ===========================================================================
// 128x128 engine (kept for the k-GEMM, N=256)
// ===========================================================================
template <typename Epi>
__global__ __launch_bounds__(256, 4)
void gemm_bt(const u16* __restrict__ A, const u16* __restrict__ B,
             long long batchStrideA, long long batchStrideB, int K, Epi epi)
{
    __shared__ __align__(16) u16 As[128 * 64];
    __shared__ __align__(16) u16 Bs[128 * 64];

    const int tid  = threadIdx.x;
    const int lane = tid & 63;
    const int w    = tid >> 6;
    const int wm   = w >> 1, wn = w & 1;
    const int bz   = blockIdx.z;

    const int gx   = gridDim.x;
    const int nwg  = gx * gridDim.y;
    const int orig = blockIdx.y * gx + blockIdx.x;
    const int swz  = ((nwg & 7) == 0) ? ((orig & 7) * (nwg >> 3) + (orig >> 3)) : orig;
    const long long m0 = (long long)(swz / gx) * 128;
    const long long n0 = (long long)(swz % gx) * 128;

    const u16* Ab = A + bz * batchStrideA;
    const u16* Bb = B + bz * batchStrideB;

    const int srow = lane >> 3;
    const int scol = ((lane & 7) ^ srow) * 8;
    const int quad = lane >> 4;
    const int l16  = lane & 15;

    const int choff0 = ((quad     ^ (l16 & 7)) * 8);
    const int choff1 = (((4 + quad) ^ (l16 & 7)) * 8);

    const f32x4 fzero = {0.f, 0.f, 0.f, 0.f};
    f32x4 acc[4][4];
#pragma unroll
    for (int i = 0; i < 4; ++i)
#pragma unroll
        for (int j = 0; j < 4; ++j) acc[i][j] = fzero;

    for (int k0 = 0; k0 < K; k0 += 64) {
        __syncthreads();
#pragma unroll
        for (int t = 0; t < 4; ++t) {
            const int rbase = w * 32 + t * 8;
            async_load16(Ab + (m0 + rbase + srow) * K + (k0 + scol), (void*)&As[rbase * 64]);
            async_load16(Bb + (n0 + rbase + srow) * K + (k0 + scol), (void*)&Bs[rbase * 64]);
        }
        __builtin_amdgcn_s_waitcnt(0);
        __syncthreads();

#pragma unroll
        for (int h = 0; h < 2; ++h) {
            const int ch = h ? choff1 : choff0;
            bf16x8 af[4], bfv[4];
#pragma unroll
            for (int mi = 0; mi < 4; ++mi)
                af[mi] = *(const bf16x8*)&As[(wm * 64 + mi * 16 + l16) * 64 + ch];
#pragma unroll
            for (int ni = 0; ni < 4; ++ni)
                bfv[ni] = *(const bf16x8*)&Bs[(wn * 64 + ni * 16 + l16) * 64 + ch];
#pragma unroll
            for (int mi = 0; mi < 4; ++mi)
#pragma unroll
                for (int ni = 0; ni < 4; ++ni)
                    acc[mi][ni] = __builtin_amdgcn_mfma_f32_16x16x32_bf16(
                        af[mi], bfv[ni], acc[mi][ni], 0, 0, 0);
        }
    }

#pragma unroll
    for (int mi = 0; mi < 4; ++mi)
#pragma unroll
        for (int ni = 0; ni < 4; ++ni)
#pragma unroll
            for (int r = 0; r < 4; ++r) {
                int m = (int)m0 + wm * 64 + mi * 16 + quad * 4 + r;
                int n = (int)n0 + wn * 64 + ni * 16 + l16;
                epi(bz, m, n, acc[mi][ni][r]);
            }
}

// ---- epilogue functors -----------------------------------------------------
struct EpiRaw {            // kraw = key@Wk^T + bk   -> fp32 (16384 x 256)
    float* out; const float* bias;
    __device__ void operator()(int, int m, int n, float v) const {
        out[(long long)m * ZN + n] = v + bias[n];
    }
};
struct EpiQru {            // base = nq@Wqru^T + bqru; split q-raw / u / r
    float* qraw; u16* u; u16* r; const float* bqru;
    __device__ void operator()(int, int m, int n, float v) const {
        v += bqru[n];
        if (n < ZN) {
            qraw[(long long)m * ZN + n] = v;
        } else if (n < ZN + EN) {
            float s = 1.f / (1.f + __expf(-v));
            u[(long long)m * EN + (n - ZN)] = f2bf(s);
        } else {
            float s = v / (1.f + __expf(-v));
            r[(long long)m * EN + (n - ZN - EN)] = f2bf(s);
        }
    }
};
struct EpiV {              // v = silu(value@Wv^T + bv), stored (b, c, e) bf16
    u16* v; const float* bv;
    __device__ void operator()(int, int m, int n, float acc) const {
        float x = acc + bv[n];
        float s = x / (1.f + __expf(-x));
        int b = m & 7, c = m >> 3;
        v[((long long)b * LN_ + c) * EN + n] = f2bf(s);
    }
};
struct EpiQK {             // attn = relu(qk*scale + bias)^2, bf16 (b, s, c)
    u16* attn; const float* relpos;
    __device__ void operator()(int bz, int m, int n, float v) const {
        float val = v * LEN_SCALE + relpos[2047 + n - m];
        float t = fmaxf(val, 0.f);
        attn[(long long)bz * LN_ * LN_ + (long long)m * LN_ + n] = f2bf(t * t);
    }
};
struct EpiH {              // hr = (attn@v) * r, bf16 rows (s*8+b)
    u16* hr; const u16* r;
    __device__ void operator()(int bz, int m, int n, float acc) const {
        long long idx = ((long long)m * BN_ + bz) * EN + n;
        hr[idx] = f2bf(acc * bf2f(r[idx]));
    }
};
struct EpiOut {            // out = query + u*((hr@Wh^T + bh) - query), fp32
    float* out; const float* query; const u16* u; const float* bh;
    __device__ void operator()(int, int m, int n, float acc) const {
        long long idx = (long long)m * EN + n;
        float qv = query[idx];
        float uu = bf2f(u[idx]);
        out[idx] = qv + uu * ((acc + bh[n]) - qv);
    }
};

// ---------------------------------------------------------------------------
// prep: LN(query)->nq bf16; cast key_in, value -> bf16.  1 block per row.
// ---------------------------------------------------------------------------
__global__ __launch_bounds__(256)
void prep_kernel(const float* __restrict__ query, const float* __restrict__ key_in,
                 const float* __restrict__ value, const float* __restrict__ ln_w,
                 const float* __restrict__ ln_b,
                 u16* __restrict__ nq, u16* __restrict__ kin, u16* __restrict__ val)
{
    __shared__ float r1[4], r2[4];
    const int m = blockIdx.x, t = threadIdx.x;
    const long long base = (long long)m * EN + t * 4;
    float4 q = *(const float4*)(query + base);
    float a1 = q.x + q.y + q.z + q.w;
    float a2 = q.x * q.x + q.y * q.y + q.z * q.z + q.w * q.w;
#pragma unroll
    for (int o = 32; o; o >>= 1) { a1 += __shfl_down(a1, o, 64); a2 += __shfl_down(a2, o, 64); }
    if ((t & 63) == 0) { r1[t >> 6] = a1; r2[t >> 6] = a2; }
    __syncthreads();
    const float S1 = r1[0] + r1[1] + r1[2] + r1[3];
    const float S2 = r2[0] + r2[1] + r2[2] + r2[3];
    const float mu = S1 * (1.f / EN);
    const float var = S2 * (1.f / EN) - mu * mu;
    const float rstd = rsqrtf(var + 1e-5f);
    const int e = t * 4;
    float4 wv = *(const float4*)(ln_w + e);
    float4 bv = *(const float4*)(ln_b + e);
    store_bf16x4(nq + base, (q.x - mu) * rstd * wv.x + bv.x, (q.y - mu) * rstd * wv.y + bv.y,
                            (q.z - mu) * rstd * wv.z + bv.z, (q.w - mu) * rstd * wv.w + bv.w);
    float4 kq = *(const float4*)(key_in + base);
    store_bf16x4(kin + base, kq.x, kq.y, kq.z, kq.w);
    float4 vq = *(const float4*)(value + base);
    store_bf16x4(val + base, vq.x, vq.y, vq.z, vq.w);
}

// ---------------------------------------------------------------------------
// l2norm over Z=256 + scale/shift; raw (16384 x 256) fp32 -> out (b, s, z) bf16
// ---------------------------------------------------------------------------
__global__ __launch_bounds__(256)
void l2norm_scale(const float* __restrict__ raw, u16* __restrict__ out,
                  const float* __restrict__ gamma, const float* __restrict__ beta)
{
    __shared__ float red[4];
    const int m = blockIdx.x, z = threadIdx.x;
    const float x = raw[(long long)m * ZN + z];
    float ss = x * x;
#pragma unroll
    for (int o = 32; o; o >>= 1) ss += __shfl_down(ss, o, 64);
    if ((z & 63) == 0) red[z >> 6] = ss;
    __syncthreads();
    const float tot = red[0] + red[1] + red[2] + red[3];
    const float inv = 1.f / fmaxf(sqrtf(tot), 1e-5f);
    const float res = x * inv * (gamma[z] + 1.f) + beta[z];
    const int b = m & 7, s = m >> 3;
    out[((long long)b * LN_ + s) * ZN + z] = f2bf(res);
}

// ---------------------------------------------------------------------------
// transpose v (b, c, e) -> vT (b, e, c), bf16, 64x64 LDS tiles
// ---------------------------------------------------------------------------
__global__ __launch_bounds__(256)
void transpose_bc(const u16* __restrict__ v, u16* __restrict__ vT)
{
    __shared__ u16 tile[64][65];
    const int b = blockIdx.z;
    const int c0 = blockIdx.y * 64, e0 = blockIdx.x * 64;
    const int tx = threadIdx.x & 63, ty = threadIdx.x >> 6;
    const u16* src = v + (long long)b * LN_ * EN;
    u16* dst = vT + (long long)b * EN * LN_;
#pragma unroll
    for (int i = 0; i < 64; i += 4)
        tile[ty + i][tx] = src[(long long)(c0 + ty + i) * EN + (e0 + tx)];
    __syncthreads();
#pragma unroll
    for (int i = 0; i < 64; i += 4)
        dst[(long long)(e0 + ty + i) * LN_ + (c0 + tx)] = tile[tx][ty + i];
}

// ---------------------------------------------------------------------------
__global__ __launch_bounds__(256)
void castw(const float* __restrict__ in, u16* __restrict__ out, int n4)
{
    const int i = blockIdx.x * 256 + threadIdx.x;
    if (i < n4) {
        float4 x = ((const float4*)in)[i];
        store_bf16x4(out + (long long)i * 4, x.x, x.y, x.z, x.w);
    }
}

// ---------------------------------------------------------------------------
extern "C" void kernel_launch(void* const* d_in, const int* in_sizes, int n_in,
                              void* d_out, int out_size, void* d_ws, size_t ws_size,
                              hipStream_t stream)
{
    const float* query  = (const float*)d_in[0];
    const float* key_in = (const float*)d_in[1];
    const float* value  = (const float*)d_in[2];
    const float* ln_w   = (const float*)d_in[3];
    const float* ln_b   = (const float*)d_in[4];
    const float* Wv     = (const float*)d_in[5];
    const float* bv     = (const float*)d_in[6];
    const float* Wk     = (const float*)d_in[7];
    const float* bk     = (const float*)d_in[8];
    const float* Wqru   = (const float*)d_in[9];
    const float* bqru   = (const float*)d_in[10];
    const float* Wh     = (const float*)d_in[11];
    const float* bh     = (const float*)d_in[12];
    const float* gamma  = (const float*)d_in[13];
    const float* beta   = (const float*)d_in[14];
    const float* relpos = (const float*)d_in[15];
    float* out = (float*)d_out;

    char* ws = (char*)d_ws;
    const size_t MB = 1ull << 20;
    u16*   nq    = (u16*)(ws + 0);          // 32 MiB, dead after GEMM-qru
    u16*   kin   = (u16*)(ws + 32 * MB);    // 32 MiB, dead after GEMM-k
    u16*   vbce  = (u16*)(ws + 32 * MB);    // 32 MiB (aliases kin)
    u16*   attn  = (u16*)(ws + 0);          // 64 MiB (aliases nq+kin/vbce)
    u16*   valb  = (u16*)(ws + 64 * MB);    // 32 MiB, dead after GEMM-v
    u16*   hr    = (u16*)(ws + 64 * MB);    // 32 MiB (aliases valb)
    u16*   qb    = (u16*)(ws + 96 * MB);    // 8 MiB  (b,s,z)
    u16*   kb    = (u16*)(ws + 104 * MB);   // 8 MiB  (b,c,z)
    u16*   ub    = (u16*)(ws + 112 * MB);   // 32 MiB
    u16*   rb    = (u16*)(ws + 144 * MB);   // 32 MiB
    u16*   vT    = (u16*)(ws + 176 * MB);   // 32 MiB (b,e,c)
    float* raw   = (float*)(ws + 208 * MB); // 16 MiB (kraw then qraw)
    u16*   WqruB = (u16*)(ws + 224 * MB);   // 4.5 MiB
    u16*   WkB   = (u16*)(ws + 229 * MB);   // 0.5 MiB
    u16*   WvB   = (u16*)(ws + 230 * MB);   // 2 MiB
    u16*   WhB   = (u16*)(ws + 232 * MB);   // 2 MiB   (total 234 MiB)
    (void)ws_size; (void)in_sizes; (void)n_in; (void)out_size;

    // 1) cast weights to bf16
    castw<<<dim3(QRU_N * EN / 4 / 256), 256, 0, stream>>>(Wqru, WqruB, QRU_N * EN / 4);
    castw<<<dim3(ZN * EN / 4 / 256), 256, 0, stream>>>(Wk, WkB, ZN * EN / 4);
    castw<<<dim3(EN * EN / 4 / 256), 256, 0, stream>>>(Wv, WvB, EN * EN / 4);
    castw<<<dim3(EN * EN / 4 / 256), 256, 0, stream>>>(Wh, WhB, EN * EN / 4);

    // 2) layernorm(query) + bf16 casts of key/value
    prep_kernel<<<dim3(MROWS), 256, 0, stream>>>(query, key_in, value, ln_w, ln_b, nq, kin, valb);

    // 3) k = l2norm(key@Wk^T + bk)*g1 + beta1   (128^2 engine: N=256)
    gemm_bt<<<dim3(ZN / 128, MROWS / 128, 1), 256, 0, stream>>>(
        kin, WkB, 0LL, 0LL, EN, EpiRaw{raw, bk});
    l2norm_scale<<<dim3(MROWS), 256, 0, stream>>>(raw, kb, gamma + ZN, beta + ZN);

    // 4) base = nq@Wqru^T + bqru -> qraw / u / r   (9 x 64 blocks)
    gemm256<<<dim3(QRU_N / 256, MROWS / 256, 1), 512, 0, stream>>>(
        nq, WqruB, 0LL, 0LL, EN, EpiQru{raw, ub, rb, bqru});
    l2norm_scale<<<dim3(MROWS), 256, 0, stream>>>(raw, qb, gamma, beta);

    // 5) v = silu(value@Wv^T + bv)  (b,c,e), then transpose to (b,e,c)
    gemm256<<<dim3(EN / 256, MROWS / 256, 1), 512, 0, stream>>>(
        valb, WvB, 0LL, 0LL, EN, EpiV{vbce, bv});
    transpose_bc<<<dim3(EN / 64, LN_ / 64, BN_), 256, 0, stream>>>(vbce, vT);

    // 6) attn = relu(q@k^T * scale + bias)^2   (8 x 8 x 8 blocks, K=256)
    gemm256<<<dim3(LN_ / 256, LN_ / 256, BN_), 512, 0, stream>>>(
        qb, kb, (long long)LN_ * ZN, (long long)LN_ * ZN, ZN, EpiQK{attn, relpos});

    // 7) hr = (attn @ v) * r   (4 x 8 x 8 blocks, K=2048)
    gemm256<<<dim3(EN / 256, LN_ / 256, BN_), 512, 0, stream>>>(
        attn, vT, (long long)LN_ * LN_, (long long)EN * LN_, LN_, EpiH{hr, rb});

    // 8) out = query + u*((hr@Wh^T + bh) - query)
    gemm256<<<dim3(EN / 256, MROWS / 256, 1), 512, 0, stream>>>(
        hr, WhB, 0LL, 0LL, EN, EpiOut{out, query, ub, bh});
}

// Round 6
// 692.233 us; speedup vs baseline: 1.1114x; 1.1114x over previous
//
#include <hip/hip_runtime.h>
#include <cstdint>

// ---------------------------------------------------------------------------
// GatedCrossAttention  (E=1024, Z=256, L=2048, B=8)
// Round 6: round-3 proven config (128^2 m97-style engine + T1 XCD swizzle)
// + merged weight-cast kernel + merged l2norm (fewer launches).
// ---------------------------------------------------------------------------

#define EN 1024
#define ZN 256
#define LN_ 2048
#define BN_ 8
#define MROWS (LN_ * BN_)          // 16384
#define QRU_N (2 * EN + ZN)        // 2304
#define LEN_SCALE 0.022097086912079608f  // 1/sqrt(2048)

typedef unsigned short u16;
typedef __bf16 bf16x8 __attribute__((ext_vector_type(8)));
typedef float f32x4 __attribute__((ext_vector_type(4)));

// ---- bf16 helpers ---------------------------------------------------------
__device__ __forceinline__ u16 f2bf(float f) {
    unsigned int u = __float_as_uint(f);
    u = (u + 0x7fff + ((u >> 16) & 1)) >> 16;
    return (u16)u;
}
__device__ __forceinline__ float bf2f(u16 s) {
    return __uint_as_float(((unsigned int)s) << 16);
}
__device__ __forceinline__ void store_bf16x4(u16* p, float a, float b, float c, float d) {
    union { u16 h[4]; uint2 v; } pk;
    pk.h[0] = f2bf(a); pk.h[1] = f2bf(b); pk.h[2] = f2bf(c); pk.h[3] = f2bf(d);
    *(uint2*)p = pk.v;
}

// ---- async global->LDS (16B/lane, wave-uniform LDS base + lane*16) --------
__device__ __forceinline__ void async_load16(const void* g, void* l) {
    __builtin_amdgcn_global_load_lds(
        (const __attribute__((address_space(1))) void*)g,
        (__attribute__((address_space(3))) void*)l,
        16, 0, 0);
}

// ---------------------------------------------------------------------------
// GEMM-BT: C[M,N] = A[M,K] @ B[N,K]^T, A/B bf16 row-major, epilogue functor.
// Block 256 (4 waves, 2x2 wave grid), tile 128x128, BK=64.
// LDS rows are 64 elems (128 B = all 32 banks); the 16B chunk index is
// XOR-swizzled by (row&7) so ds_read_b128 spreads 2 lanes/bank (free, m136).
// Swizzle is applied on the GLOBAL source address of global_load_lds (the
// LDS destination is hardware-fixed at base+lane*16) and undone on read.
// T1: XCD-aware block swizzle (bijective; all grids here have nwg % 8 == 0).
// Requires M%128==0, N%128==0, K%64==0.
// ---------------------------------------------------------------------------
template <typename Epi>
__global__ __launch_bounds__(256, 4)
void gemm_bt(const u16* __restrict__ A, const u16* __restrict__ B,
             long long batchStrideA, long long batchStrideB, int K, Epi epi)
{
    __shared__ __align__(16) u16 As[128 * 64];
    __shared__ __align__(16) u16 Bs[128 * 64];

    const int tid  = threadIdx.x;
    const int lane = tid & 63;
    const int w    = tid >> 6;
    const int wm   = w >> 1, wn = w & 1;
    const int bz   = blockIdx.z;

    // T1: XCD-aware swizzle of the (x,y) block index
    const int gx   = gridDim.x;
    const int nwg  = gx * gridDim.y;
    const int orig = blockIdx.y * gx + blockIdx.x;
    const int swz  = ((nwg & 7) == 0) ? ((orig & 7) * (nwg >> 3) + (orig >> 3)) : orig;
    const long long m0 = (long long)(swz / gx) * 128;
    const long long n0 = (long long)(swz % gx) * 128;

    const u16* Ab = A + bz * batchStrideA;
    const u16* Bb = B + bz * batchStrideB;

    // staging: lane covers row (lane>>3) of each 8-row group, swizzled chunk
    const int srow = lane >> 3;                          // 0..7
    const int scol = ((lane & 7) ^ srow) * 8;            // swizzled source col
    const int quad = lane >> 4;
    const int l16  = lane & 15;

    // read-side swizzled chunk offsets (elems), constant per lane
    const int choff0 = ((quad     ^ (l16 & 7)) * 8);     // k-half 0
    const int choff1 = (((4 + quad) ^ (l16 & 7)) * 8);   // k-half 1

    const f32x4 fzero = {0.f, 0.f, 0.f, 0.f};
    f32x4 acc[4][4];
#pragma unroll
    for (int i = 0; i < 4; ++i)
#pragma unroll
        for (int j = 0; j < 4; ++j) acc[i][j] = fzero;

    for (int k0 = 0; k0 < K; k0 += 64) {
        __syncthreads();   // prior-iter LDS reads done before overwrite
#pragma unroll
        for (int t = 0; t < 4; ++t) {
            const int rbase = w * 32 + t * 8;
            async_load16(Ab + (m0 + rbase + srow) * K + (k0 + scol), (void*)&As[rbase * 64]);
            async_load16(Bb + (n0 + rbase + srow) * K + (k0 + scol), (void*)&Bs[rbase * 64]);
        }
        __builtin_amdgcn_s_waitcnt(0);
        __syncthreads();

#pragma unroll
        for (int h = 0; h < 2; ++h) {
            const int ch = h ? choff1 : choff0;
            bf16x8 af[4], bfv[4];
#pragma unroll
            for (int mi = 0; mi < 4; ++mi)
                af[mi] = *(const bf16x8*)&As[(wm * 64 + mi * 16 + l16) * 64 + ch];
#pragma unroll
            for (int ni = 0; ni < 4; ++ni)
                bfv[ni] = *(const bf16x8*)&Bs[(wn * 64 + ni * 16 + l16) * 64 + ch];
#pragma unroll
            for (int mi = 0; mi < 4; ++mi)
#pragma unroll
                for (int ni = 0; ni < 4; ++ni)
                    acc[mi][ni] = __builtin_amdgcn_mfma_f32_16x16x32_bf16(
                        af[mi], bfv[ni], acc[mi][ni], 0, 0, 0);
        }
    }

    // epilogue: D[row][col], col = lane&15, row = quad*4 + reg  [verified m89/m91]
#pragma unroll
    for (int mi = 0; mi < 4; ++mi)
#pragma unroll
        for (int ni = 0; ni < 4; ++ni)
#pragma unroll
            for (int r = 0; r < 4; ++r) {
                int m = (int)m0 + wm * 64 + mi * 16 + quad * 4 + r;
                int n = (int)n0 + wn * 64 + ni * 16 + l16;
                epi(bz, m, n, acc[mi][ni][r]);
            }
}

// ---- epilogue functors -----------------------------------------------------
struct EpiRaw {            // kraw = key@Wk^T + bk   -> fp32 (16384 x 256)
    float* out; const float* bias;
    __device__ void operator()(int, int m, int n, float v) const {
        out[(long long)m * ZN + n] = v + bias[n];
    }
};
struct EpiQru {            // base = nq@Wqru^T + bqru; split q-raw / u / r
    float* qraw; u16* u; u16* r; const float* bqru;
    __device__ void operator()(int, int m, int n, float v) const {
        v += bqru[n];
        if (n < ZN) {
            qraw[(long long)m * ZN + n] = v;
        } else if (n < ZN + EN) {
            float s = 1.f / (1.f + __expf(-v));
            u[(long long)m * EN + (n - ZN)] = f2bf(s);
        } else {
            float s = v / (1.f + __expf(-v));
            r[(long long)m * EN + (n - ZN - EN)] = f2bf(s);
        }
    }
};
struct EpiV {              // v = silu(value@Wv^T + bv), stored (b, c, e) bf16
    u16* v; const float* bv;
    __device__ void operator()(int, int m, int n, float acc) const {
        float x = acc + bv[n];
        float s = x / (1.f + __expf(-x));
        int b = m & 7, c = m >> 3;
        v[((long long)b * LN_ + c) * EN + n] = f2bf(s);
    }
};
struct EpiQK {             // attn = relu(qk*scale + bias)^2, bf16 (b, s, c)
    u16* attn; const float* relpos;
    __device__ void operator()(int bz, int m, int n, float v) const {
        float val = v * LEN_SCALE + relpos[2047 + n - m];
        float t = fmaxf(val, 0.f);
        attn[(long long)bz * LN_ * LN_ + (long long)m * LN_ + n] = f2bf(t * t);
    }
};
struct EpiH {              // hr = (attn@v) * r, bf16 rows (s*8+b)
    u16* hr; const u16* r;
    __device__ void operator()(int bz, int m, int n, float acc) const {
        long long idx = ((long long)m * BN_ + bz) * EN + n;
        hr[idx] = f2bf(acc * bf2f(r[idx]));
    }
};
struct EpiOut {            // out = query + u*((hr@Wh^T + bh) - query), fp32
    float* out; const float* query; const u16* u; const float* bh;
    __device__ void operator()(int, int m, int n, float acc) const {
        long long idx = (long long)m * EN + n;
        float qv = query[idx];
        float uu = bf2f(u[idx]);
        out[idx] = qv + uu * ((acc + bh[n]) - qv);
    }
};

// ---------------------------------------------------------------------------
// prep: LN(query)->nq bf16; cast key_in, value -> bf16.  1 block per row.
// ---------------------------------------------------------------------------
__global__ __launch_bounds__(256)
void prep_kernel(const float* __restrict__ query, const float* __restrict__ key_in,
                 const float* __restrict__ value, const float* __restrict__ ln_w,
                 const float* __restrict__ ln_b,
                 u16* __restrict__ nq, u16* __restrict__ kin, u16* __restrict__ val)
{
    __shared__ float r1[4], r2[4];
    const int m = blockIdx.x, t = threadIdx.x;
    const long long base = (long long)m * EN + t * 4;
    float4 q = *(const float4*)(query + base);
    float a1 = q.x + q.y + q.z + q.w;
    float a2 = q.x * q.x + q.y * q.y + q.z * q.z + q.w * q.w;
#pragma unroll
    for (int o = 32; o; o >>= 1) { a1 += __shfl_down(a1, o, 64); a2 += __shfl_down(a2, o, 64); }
    if ((t & 63) == 0) { r1[t >> 6] = a1; r2[t >> 6] = a2; }
    __syncthreads();
    const float S1 = r1[0] + r1[1] + r1[2] + r1[3];
    const float S2 = r2[0] + r2[1] + r2[2] + r2[3];
    const float mu = S1 * (1.f / EN);
    const float var = S2 * (1.f / EN) - mu * mu;
    const float rstd = rsqrtf(var + 1e-5f);
    const int e = t * 4;
    float4 wv = *(const float4*)(ln_w + e);
    float4 bv = *(const float4*)(ln_b + e);
    store_bf16x4(nq + base, (q.x - mu) * rstd * wv.x + bv.x, (q.y - mu) * rstd * wv.y + bv.y,
                            (q.z - mu) * rstd * wv.z + bv.z, (q.w - mu) * rstd * wv.w + bv.w);
    float4 kq = *(const float4*)(key_in + base);
    store_bf16x4(kin + base, kq.x, kq.y, kq.z, kq.w);
    float4 vq = *(const float4*)(value + base);
    store_bf16x4(val + base, vq.x, vq.y, vq.z, vq.w);
}

// ---------------------------------------------------------------------------
// merged l2norm over Z=256 + scale/shift for BOTH k (y=0) and q (y=1).
// raw (16384 x 256) fp32 -> out (b, *, z) bf16
// ---------------------------------------------------------------------------
__global__ __launch_bounds__(256)
void l2norm_both(const float* __restrict__ kraw, const float* __restrict__ qraw,
                 u16* __restrict__ kb, u16* __restrict__ qb,
                 const float* __restrict__ gamma, const float* __restrict__ beta)
{
    __shared__ float red[4];
    const int m = blockIdx.x, z = threadIdx.x;
    const int which = blockIdx.y;                 // 0 = k, 1 = q
    const float* raw = which ? qraw : kraw;
    u16* out = which ? qb : kb;
    const float* g = gamma + (which ? 0 : ZN);
    const float* be = beta + (which ? 0 : ZN);
    const float x = raw[(long long)m * ZN + z];
    float ss = x * x;
#pragma unroll
    for (int o = 32; o; o >>= 1) ss += __shfl_down(ss, o, 64);
    if ((z & 63) == 0) red[z >> 6] = ss;
    __syncthreads();
    const float tot = red[0] + red[1] + red[2] + red[3];
    const float inv = 1.f / fmaxf(sqrtf(tot), 1e-5f);
    const float res = x * inv * (g[z] + 1.f) + be[z];
    const int b = m & 7, s = m >> 3;
    out[((long long)b * LN_ + s) * ZN + z] = f2bf(res);
}

// ---------------------------------------------------------------------------
// transpose v (b, c, e) -> vT (b, e, c), bf16, 64x64 LDS tiles
// ---------------------------------------------------------------------------
__global__ __launch_bounds__(256)
void transpose_bc(const u16* __restrict__ v, u16* __restrict__ vT)
{
    __shared__ u16 tile[64][65];
    const int b = blockIdx.z;
    const int c0 = blockIdx.y * 64, e0 = blockIdx.x * 64;
    const int tx = threadIdx.x & 63, ty = threadIdx.x >> 6;
    const u16* src = v + (long long)b * LN_ * EN;
    u16* dst = vT + (long long)b * EN * LN_;
#pragma unroll
    for (int i = 0; i < 64; i += 4)
        tile[ty + i][tx] = src[(long long)(c0 + ty + i) * EN + (e0 + tx)];
    __syncthreads();
#pragma unroll
    for (int i = 0; i < 64; i += 4)
        dst[(long long)(e0 + ty + i) * LN_ + (c0 + tx)] = tile[tx][ty + i];
}

// ---------------------------------------------------------------------------
// merged weight cast: all four weight matrices in one grid-strided launch.
// segments (in float4 units): Wqru | Wk | Wv | Wh
// ---------------------------------------------------------------------------
#define N4_QRU (QRU_N * EN / 4)            // 589824
#define N4_K   (ZN * EN / 4)               // 65536
#define N4_V   (EN * EN / 4)               // 262144
#define N4_H   (EN * EN / 4)               // 262144
#define N4_TOT (N4_QRU + N4_K + N4_V + N4_H)

__global__ __launch_bounds__(256)
void castw_all(const float* __restrict__ Wqru, const float* __restrict__ Wk,
               const float* __restrict__ Wv,   const float* __restrict__ Wh,
               u16* __restrict__ dQru, u16* __restrict__ dK,
               u16* __restrict__ dV,   u16* __restrict__ dH)
{
    int i = blockIdx.x * 256 + threadIdx.x;
    if (i >= N4_TOT) return;
    const float* src; u16* dst; int j = i;
    if (j < N4_QRU)                { src = Wqru; dst = dQru; }
    else if ((j -= N4_QRU) < N4_K) { src = Wk;   dst = dK;   }
    else if ((j -= N4_K) < N4_V)   { src = Wv;   dst = dV;   }
    else { j -= N4_V;                src = Wh;   dst = dH;   }
    float4 x = ((const float4*)src)[j];
    store_bf16x4(dst + (long long)j * 4, x.x, x.y, x.z, x.w);
}

// ---------------------------------------------------------------------------
extern "C" void kernel_launch(void* const* d_in, const int* in_sizes, int n_in,
                              void* d_out, int out_size, void* d_ws, size_t ws_size,
                              hipStream_t stream)
{
    const float* query  = (const float*)d_in[0];
    const float* key_in = (const float*)d_in[1];
    const float* value  = (const float*)d_in[2];
    const float* ln_w   = (const float*)d_in[3];
    const float* ln_b   = (const float*)d_in[4];
    const float* Wv     = (const float*)d_in[5];
    const float* bv     = (const float*)d_in[6];
    const float* Wk     = (const float*)d_in[7];
    const float* bk     = (const float*)d_in[8];
    const float* Wqru   = (const float*)d_in[9];
    const float* bqru   = (const float*)d_in[10];
    const float* Wh     = (const float*)d_in[11];
    const float* bh     = (const float*)d_in[12];
    const float* gamma  = (const float*)d_in[13];
    const float* beta   = (const float*)d_in[14];
    const float* relpos = (const float*)d_in[15];
    float* out = (float*)d_out;

    char* ws = (char*)d_ws;
    const size_t MB = 1ull << 20;
    // region1 (0..64MB): nq | kin -> qraw -> vbce  -> later attn (full 64MB)
    u16*   nq    = (u16*)(ws + 0);          // 32 MiB, dead after GEMM-qru
    u16*   kin   = (u16*)(ws + 32 * MB);    // 32 MiB, dead after GEMM-k
    float* qraw  = (float*)(ws + 32 * MB);  // 16 MiB (aliases kin), dead after l2norm
    u16*   vbce  = (u16*)(ws + 32 * MB);    // 32 MiB (aliases kin/qraw), dead after transpose
    u16*   attn  = (u16*)(ws + 0);          // 64 MiB (aliases nq+kin/vbce)
    // region2 (64..96MB): val -> later hr
    u16*   valb  = (u16*)(ws + 64 * MB);    // 32 MiB, dead after GEMM-v
    u16*   hr    = (u16*)(ws + 64 * MB);    // 32 MiB (aliases valb)
    // persistent region (96MB..):
    u16*   qb    = (u16*)(ws + 96 * MB);    // 8 MiB  (b,s,z)
    u16*   kb    = (u16*)(ws + 104 * MB);   // 8 MiB  (b,c,z)
    u16*   ub    = (u16*)(ws + 112 * MB);   // 32 MiB
    u16*   rb    = (u16*)(ws + 144 * MB);   // 32 MiB
    u16*   vT    = (u16*)(ws + 176 * MB);   // 32 MiB (b,e,c)
    float* kraw  = (float*)(ws + 208 * MB); // 16 MiB
    u16*   WqruB = (u16*)(ws + 224 * MB);   // 4.5 MiB
    u16*   WkB   = (u16*)(ws + 229 * MB);   // 0.5 MiB
    u16*   WvB   = (u16*)(ws + 230 * MB);   // 2 MiB
    u16*   WhB   = (u16*)(ws + 232 * MB);   // 2 MiB   (total 234 MiB)
    (void)ws_size; (void)in_sizes; (void)n_in; (void)out_size;

    // 1) cast all weights to bf16 (single launch)
    castw_all<<<dim3((N4_TOT + 255) / 256), 256, 0, stream>>>(
        Wqru, Wk, Wv, Wh, WqruB, WkB, WvB, WhB);

    // 2) layernorm(query) + bf16 casts of key/value
    prep_kernel<<<dim3(MROWS), 256, 0, stream>>>(query, key_in, value, ln_w, ln_b, nq, kin, valb);

    // 3) kraw = key@Wk^T + bk
    gemm_bt<<<dim3(ZN / 128, MROWS / 128, 1), 256, 0, stream>>>(
        kin, WkB, 0LL, 0LL, EN, EpiRaw{kraw, bk});

    // 4) base = nq@Wqru^T + bqru -> qraw / u / r   (kin dead -> qraw region)
    gemm_bt<<<dim3(QRU_N / 128, MROWS / 128, 1), 256, 0, stream>>>(
        nq, WqruB, 0LL, 0LL, EN, EpiQru{qraw, ub, rb, bqru});

    // 5) merged l2norm for k and q
    l2norm_both<<<dim3(MROWS, 2), 256, 0, stream>>>(kraw, qraw, kb, qb, gamma, beta);

    // 6) v = silu(value@Wv^T + bv)  (b,c,e), then transpose to (b,e,c)
    gemm_bt<<<dim3(EN / 128, MROWS / 128, 1), 256, 0, stream>>>(
        valb, WvB, 0LL, 0LL, EN, EpiV{vbce, bv});
    transpose_bc<<<dim3(EN / 64, LN_ / 64, BN_), 256, 0, stream>>>(vbce, vT);

    // 7) attn = relu(q@k^T * scale + bias)^2   (batched over b)
    gemm_bt<<<dim3(LN_ / 128, LN_ / 128, BN_), 256, 0, stream>>>(
        qb, kb, (long long)LN_ * ZN, (long long)LN_ * ZN, ZN, EpiQK{attn, relpos});

    // 8) hr = (attn @ v) * r   (batched over b)
    gemm_bt<<<dim3(EN / 128, LN_ / 128, BN_), 256, 0, stream>>>(
        attn, vT, (long long)LN_ * LN_, (long long)EN * LN_, LN_, EpiH{hr, rb});

    // 9) out = query + u*((hr@Wh^T + bh) - query)
    gemm_bt<<<dim3(EN / 128, MROWS / 128, 1), 256, 0, stream>>>(
        hr, WhB, 0LL, 0LL, EN, EpiOut{out, query, ub, bh});
}

// Round 7
// 678.470 us; speedup vs baseline: 1.1339x; 1.0203x over previous
//
#include <hip/hip_runtime.h>
#include <cstdint>

// ---------------------------------------------------------------------------
// GatedCrossAttention  (E=1024, Z=256, L=2048, B=8)
// Round 7: round-6 config + fully vectorized transpose (16B both ways) and
// wave-per-row prep (no block barrier).  GEMM engines untouched.
// ---------------------------------------------------------------------------

#define EN 1024
#define ZN 256
#define LN_ 2048
#define BN_ 8
#define MROWS (LN_ * BN_)          // 16384
#define QRU_N (2 * EN + ZN)        // 2304
#define LEN_SCALE 0.022097086912079608f  // 1/sqrt(2048)

typedef unsigned short u16;
typedef __bf16 bf16x8 __attribute__((ext_vector_type(8)));
typedef float f32x4 __attribute__((ext_vector_type(4)));

// ---- bf16 helpers ---------------------------------------------------------
__device__ __forceinline__ u16 f2bf(float f) {
    unsigned int u = __float_as_uint(f);
    u = (u + 0x7fff + ((u >> 16) & 1)) >> 16;
    return (u16)u;
}
__device__ __forceinline__ float bf2f(u16 s) {
    return __uint_as_float(((unsigned int)s) << 16);
}
__device__ __forceinline__ void store_bf16x4(u16* p, float a, float b, float c, float d) {
    union { u16 h[4]; uint2 v; } pk;
    pk.h[0] = f2bf(a); pk.h[1] = f2bf(b); pk.h[2] = f2bf(c); pk.h[3] = f2bf(d);
    *(uint2*)p = pk.v;
}

// ---- async global->LDS (16B/lane, wave-uniform LDS base + lane*16) --------
__device__ __forceinline__ void async_load16(const void* g, void* l) {
    __builtin_amdgcn_global_load_lds(
        (const __attribute__((address_space(1))) void*)g,
        (__attribute__((address_space(3))) void*)l,
        16, 0, 0);
}

// ---------------------------------------------------------------------------
// GEMM-BT: C[M,N] = A[M,K] @ B[N,K]^T, A/B bf16 row-major, epilogue functor.
// Block 256 (4 waves, 2x2 wave grid), tile 128x128, BK=64.
// LDS rows are 64 elems (128 B = all 32 banks); the 16B chunk index is
// XOR-swizzled by (row&7) so ds_read_b128 spreads 2 lanes/bank (free, m136).
// Swizzle is applied on the GLOBAL source address of global_load_lds (the
// LDS destination is hardware-fixed at base+lane*16) and undone on read.
// T1: XCD-aware block swizzle (bijective; all grids here have nwg % 8 == 0).
// Requires M%128==0, N%128==0, K%64==0.
// ---------------------------------------------------------------------------
template <typename Epi>
__global__ __launch_bounds__(256, 4)
void gemm_bt(const u16* __restrict__ A, const u16* __restrict__ B,
             long long batchStrideA, long long batchStrideB, int K, Epi epi)
{
    __shared__ __align__(16) u16 As[128 * 64];
    __shared__ __align__(16) u16 Bs[128 * 64];

    const int tid  = threadIdx.x;
    const int lane = tid & 63;
    const int w    = tid >> 6;
    const int wm   = w >> 1, wn = w & 1;
    const int bz   = blockIdx.z;

    // T1: XCD-aware swizzle of the (x,y) block index
    const int gx   = gridDim.x;
    const int nwg  = gx * gridDim.y;
    const int orig = blockIdx.y * gx + blockIdx.x;
    const int swz  = ((nwg & 7) == 0) ? ((orig & 7) * (nwg >> 3) + (orig >> 3)) : orig;
    const long long m0 = (long long)(swz / gx) * 128;
    const long long n0 = (long long)(swz % gx) * 128;

    const u16* Ab = A + bz * batchStrideA;
    const u16* Bb = B + bz * batchStrideB;

    // staging: lane covers row (lane>>3) of each 8-row group, swizzled chunk
    const int srow = lane >> 3;                          // 0..7
    const int scol = ((lane & 7) ^ srow) * 8;            // swizzled source col
    const int quad = lane >> 4;
    const int l16  = lane & 15;

    // read-side swizzled chunk offsets (elems), constant per lane
    const int choff0 = ((quad     ^ (l16 & 7)) * 8);     // k-half 0
    const int choff1 = (((4 + quad) ^ (l16 & 7)) * 8);   // k-half 1

    const f32x4 fzero = {0.f, 0.f, 0.f, 0.f};
    f32x4 acc[4][4];
#pragma unroll
    for (int i = 0; i < 4; ++i)
#pragma unroll
        for (int j = 0; j < 4; ++j) acc[i][j] = fzero;

    for (int k0 = 0; k0 < K; k0 += 64) {
        __syncthreads();   // prior-iter LDS reads done before overwrite
#pragma unroll
        for (int t = 0; t < 4; ++t) {
            const int rbase = w * 32 + t * 8;
            async_load16(Ab + (m0 + rbase + srow) * K + (k0 + scol), (void*)&As[rbase * 64]);
            async_load16(Bb + (n0 + rbase + srow) * K + (k0 + scol), (void*)&Bs[rbase * 64]);
        }
        __builtin_amdgcn_s_waitcnt(0);
        __syncthreads();

#pragma unroll
        for (int h = 0; h < 2; ++h) {
            const int ch = h ? choff1 : choff0;
            bf16x8 af[4], bfv[4];
#pragma unroll
            for (int mi = 0; mi < 4; ++mi)
                af[mi] = *(const bf16x8*)&As[(wm * 64 + mi * 16 + l16) * 64 + ch];
#pragma unroll
            for (int ni = 0; ni < 4; ++ni)
                bfv[ni] = *(const bf16x8*)&Bs[(wn * 64 + ni * 16 + l16) * 64 + ch];
#pragma unroll
            for (int mi = 0; mi < 4; ++mi)
#pragma unroll
                for (int ni = 0; ni < 4; ++ni)
                    acc[mi][ni] = __builtin_amdgcn_mfma_f32_16x16x32_bf16(
                        af[mi], bfv[ni], acc[mi][ni], 0, 0, 0);
        }
    }

    // epilogue: D[row][col], col = lane&15, row = quad*4 + reg  [verified m89/m91]
#pragma unroll
    for (int mi = 0; mi < 4; ++mi)
#pragma unroll
        for (int ni = 0; ni < 4; ++ni)
#pragma unroll
            for (int r = 0; r < 4; ++r) {
                int m = (int)m0 + wm * 64 + mi * 16 + quad * 4 + r;
                int n = (int)n0 + wn * 64 + ni * 16 + l16;
                epi(bz, m, n, acc[mi][ni][r]);
            }
}

// ---- epilogue functors -----------------------------------------------------
struct EpiRaw {            // kraw = key@Wk^T + bk   -> fp32 (16384 x 256)
    float* out; const float* bias;
    __device__ void operator()(int, int m, int n, float v) const {
        out[(long long)m * ZN + n] = v + bias[n];
    }
};
struct EpiQru {            // base = nq@Wqru^T + bqru; split q-raw / u / r
    float* qraw; u16* u; u16* r; const float* bqru;
    __device__ void operator()(int, int m, int n, float v) const {
        v += bqru[n];
        if (n < ZN) {
            qraw[(long long)m * ZN + n] = v;
        } else if (n < ZN + EN) {
            float s = 1.f / (1.f + __expf(-v));
            u[(long long)m * EN + (n - ZN)] = f2bf(s);
        } else {
            float s = v / (1.f + __expf(-v));
            r[(long long)m * EN + (n - ZN - EN)] = f2bf(s);
        }
    }
};
struct EpiV {              // v = silu(value@Wv^T + bv), stored (b, c, e) bf16
    u16* v; const float* bv;
    __device__ void operator()(int, int m, int n, float acc) const {
        float x = acc + bv[n];
        float s = x / (1.f + __expf(-x));
        int b = m & 7, c = m >> 3;
        v[((long long)b * LN_ + c) * EN + n] = f2bf(s);
    }
};
struct EpiQK {             // attn = relu(qk*scale + bias)^2, bf16 (b, s, c)
    u16* attn; const float* relpos;
    __device__ void operator()(int bz, int m, int n, float v) const {
        float val = v * LEN_SCALE + relpos[2047 + n - m];
        float t = fmaxf(val, 0.f);
        attn[(long long)bz * LN_ * LN_ + (long long)m * LN_ + n] = f2bf(t * t);
    }
};
struct EpiH {              // hr = (attn@v) * r, bf16 rows (s*8+b)
    u16* hr; const u16* r;
    __device__ void operator()(int bz, int m, int n, float acc) const {
        long long idx = ((long long)m * BN_ + bz) * EN + n;
        hr[idx] = f2bf(acc * bf2f(r[idx]));
    }
};
struct EpiOut {            // out = query + u*((hr@Wh^T + bh) - query), fp32
    float* out; const float* query; const u16* u; const float* bh;
    __device__ void operator()(int, int m, int n, float acc) const {
        long long idx = (long long)m * EN + n;
        float qv = query[idx];
        float uu = bf2f(u[idx]);
        out[idx] = qv + uu * ((acc + bh[n]) - qv);
    }
};

// ---------------------------------------------------------------------------
// prep: LN(query)->nq bf16; cast key_in, value -> bf16.
// One WAVE per row (block = 4 rows); wave-local shuffle reduce, no barrier.
// ---------------------------------------------------------------------------
__global__ __launch_bounds__(256)
void prep_kernel(const float* __restrict__ query, const float* __restrict__ key_in,
                 const float* __restrict__ value, const float* __restrict__ ln_w,
                 const float* __restrict__ ln_b,
                 u16* __restrict__ nq, u16* __restrict__ kin, u16* __restrict__ val)
{
    const int w = threadIdx.x >> 6, lane = threadIdx.x & 63;
    const int m = blockIdx.x * 4 + w;
    const long long rowb = (long long)m * EN;

    float4 q[4];
    float a1 = 0.f, a2 = 0.f;
#pragma unroll
    for (int p = 0; p < 4; ++p) {
        q[p] = *(const float4*)(query + rowb + p * 256 + lane * 4);
        a1 += q[p].x + q[p].y + q[p].z + q[p].w;
        a2 += q[p].x * q[p].x + q[p].y * q[p].y + q[p].z * q[p].z + q[p].w * q[p].w;
    }
#pragma unroll
    for (int o = 32; o; o >>= 1) { a1 += __shfl_down(a1, o, 64); a2 += __shfl_down(a2, o, 64); }
    const float S1 = __shfl(a1, 0, 64);
    const float S2 = __shfl(a2, 0, 64);
    const float mu = S1 * (1.f / EN);
    const float var = S2 * (1.f / EN) - mu * mu;
    const float rstd = rsqrtf(var + 1e-5f);

#pragma unroll
    for (int p = 0; p < 4; ++p) {
        const long long off = rowb + p * 256 + lane * 4;
        const int e = p * 256 + lane * 4;
        float4 wv = *(const float4*)(ln_w + e);
        float4 bv = *(const float4*)(ln_b + e);
        store_bf16x4(nq + off,
                     (q[p].x - mu) * rstd * wv.x + bv.x, (q[p].y - mu) * rstd * wv.y + bv.y,
                     (q[p].z - mu) * rstd * wv.z + bv.z, (q[p].w - mu) * rstd * wv.w + bv.w);
        float4 kq = *(const float4*)(key_in + off);
        store_bf16x4(kin + off, kq.x, kq.y, kq.z, kq.w);
        float4 vq = *(const float4*)(value + off);
        store_bf16x4(val + off, vq.x, vq.y, vq.z, vq.w);
    }
}

// ---------------------------------------------------------------------------
// merged l2norm over Z=256 + scale/shift for BOTH k (y=0) and q (y=1).
// raw (16384 x 256) fp32 -> out (b, *, z) bf16
// ---------------------------------------------------------------------------
__global__ __launch_bounds__(256)
void l2norm_both(const float* __restrict__ kraw, const float* __restrict__ qraw,
                 u16* __restrict__ kb, u16* __restrict__ qb,
                 const float* __restrict__ gamma, const float* __restrict__ beta)
{
    __shared__ float red[4];
    const int m = blockIdx.x, z = threadIdx.x;
    const int which = blockIdx.y;                 // 0 = k, 1 = q
    const float* raw = which ? qraw : kraw;
    u16* out = which ? qb : kb;
    const float* g = gamma + (which ? 0 : ZN);
    const float* be = beta + (which ? 0 : ZN);
    const float x = raw[(long long)m * ZN + z];
    float ss = x * x;
#pragma unroll
    for (int o = 32; o; o >>= 1) ss += __shfl_down(ss, o, 64);
    if ((z & 63) == 0) red[z >> 6] = ss;
    __syncthreads();
    const float tot = red[0] + red[1] + red[2] + red[3];
    const float inv = 1.f / fmaxf(sqrtf(tot), 1e-5f);
    const float res = x * inv * (g[z] + 1.f) + be[z];
    const int b = m & 7, s = m >> 3;
    out[((long long)b * LN_ + s) * ZN + z] = f2bf(res);
}

// ---------------------------------------------------------------------------
// transpose v (b, c, e) -> vT (b, e, c), bf16, 64x64 LDS tiles.
// 16 B global loads AND stores; scalar LDS with [64][65] pad (2-way = free).
// ---------------------------------------------------------------------------
__global__ __launch_bounds__(256)
void transpose_bc(const u16* __restrict__ v, u16* __restrict__ vT)
{
    __shared__ u16 tile[64][65];
    const int b = blockIdx.z;
    const int c0 = blockIdx.y * 64, e0 = blockIdx.x * 64;
    const int t  = threadIdx.x;
    const int rc = t >> 3;        // 0..31
    const int ec = t & 7;         // 0..7  (8-elem chunk)
    const u16* src = v + (long long)b * LN_ * EN;
    u16* dst = vT + (long long)b * EN * LN_;

#pragma unroll
    for (int i = 0; i < 64; i += 32) {
        union { uint4 v4; u16 h[8]; } ld;
        ld.v4 = *(const uint4*)(src + (long long)(c0 + rc + i) * EN + (e0 + ec * 8));
#pragma unroll
        for (int j = 0; j < 8; ++j) tile[rc + i][ec * 8 + j] = ld.h[j];
    }
    __syncthreads();
#pragma unroll
    for (int i = 0; i < 64; i += 32) {
        union { uint4 v4; u16 h[8]; } st;
#pragma unroll
        for (int j = 0; j < 8; ++j) st.h[j] = tile[ec * 8 + j][rc + i];
        *(uint4*)(dst + (long long)(e0 + rc + i) * LN_ + (c0 + ec * 8)) = st.v4;
    }
}

// ---------------------------------------------------------------------------
// merged weight cast: all four weight matrices in one grid-strided launch.
// segments (in float4 units): Wqru | Wk | Wv | Wh
// ---------------------------------------------------------------------------
#define N4_QRU (QRU_N * EN / 4)            // 589824
#define N4_K   (ZN * EN / 4)               // 65536
#define N4_V   (EN * EN / 4)               // 262144
#define N4_H   (EN * EN / 4)               // 262144
#define N4_TOT (N4_QRU + N4_K + N4_V + N4_H)

__global__ __launch_bounds__(256)
void castw_all(const float* __restrict__ Wqru, const float* __restrict__ Wk,
               const float* __restrict__ Wv,   const float* __restrict__ Wh,
               u16* __restrict__ dQru, u16* __restrict__ dK,
               u16* __restrict__ dV,   u16* __restrict__ dH)
{
    int i = blockIdx.x * 256 + threadIdx.x;
    if (i >= N4_TOT) return;
    const float* src; u16* dst; int j = i;
    if (j < N4_QRU)                { src = Wqru; dst = dQru; }
    else if ((j -= N4_QRU) < N4_K) { src = Wk;   dst = dK;   }
    else if ((j -= N4_K) < N4_V)   { src = Wv;   dst = dV;   }
    else { j -= N4_V;                src = Wh;   dst = dH;   }
    float4 x = ((const float4*)src)[j];
    store_bf16x4(dst + (long long)j * 4, x.x, x.y, x.z, x.w);
}

// ---------------------------------------------------------------------------
extern "C" void kernel_launch(void* const* d_in, const int* in_sizes, int n_in,
                              void* d_out, int out_size, void* d_ws, size_t ws_size,
                              hipStream_t stream)
{
    const float* query  = (const float*)d_in[0];
    const float* key_in = (const float*)d_in[1];
    const float* value  = (const float*)d_in[2];
    const float* ln_w   = (const float*)d_in[3];
    const float* ln_b   = (const float*)d_in[4];
    const float* Wv     = (const float*)d_in[5];
    const float* bv     = (const float*)d_in[6];
    const float* Wk     = (const float*)d_in[7];
    const float* bk     = (const float*)d_in[8];
    const float* Wqru   = (const float*)d_in[9];
    const float* bqru   = (const float*)d_in[10];
    const float* Wh     = (const float*)d_in[11];
    const float* bh     = (const float*)d_in[12];
    const float* gamma  = (const float*)d_in[13];
    const float* beta   = (const float*)d_in[14];
    const float* relpos = (const float*)d_in[15];
    float* out = (float*)d_out;

    char* ws = (char*)d_ws;
    const size_t MB = 1ull << 20;
    // region1 (0..64MB): nq | kin -> qraw -> vbce  -> later attn (full 64MB)
    u16*   nq    = (u16*)(ws + 0);          // 32 MiB, dead after GEMM-qru
    u16*   kin   = (u16*)(ws + 32 * MB);    // 32 MiB, dead after GEMM-k
    float* qraw  = (float*)(ws + 32 * MB);  // 16 MiB (aliases kin), dead after l2norm
    u16*   vbce  = (u16*)(ws + 32 * MB);    // 32 MiB (aliases kin/qraw), dead after transpose
    u16*   attn  = (u16*)(ws + 0);          // 64 MiB (aliases nq+kin/vbce)
    // region2 (64..96MB): val -> later hr
    u16*   valb  = (u16*)(ws + 64 * MB);    // 32 MiB, dead after GEMM-v
    u16*   hr    = (u16*)(ws + 64 * MB);    // 32 MiB (aliases valb)
    // persistent region (96MB..):
    u16*   qb    = (u16*)(ws + 96 * MB);    // 8 MiB  (b,s,z)
    u16*   kb    = (u16*)(ws + 104 * MB);   // 8 MiB  (b,c,z)
    u16*   ub    = (u16*)(ws + 112 * MB);   // 32 MiB
    u16*   rb    = (u16*)(ws + 144 * MB);   // 32 MiB
    u16*   vT    = (u16*)(ws + 176 * MB);   // 32 MiB (b,e,c)
    float* kraw  = (float*)(ws + 208 * MB); // 16 MiB
    u16*   WqruB = (u16*)(ws + 224 * MB);   // 4.5 MiB
    u16*   WkB   = (u16*)(ws + 229 * MB);   // 0.5 MiB
    u16*   WvB   = (u16*)(ws + 230 * MB);   // 2 MiB
    u16*   WhB   = (u16*)(ws + 232 * MB);   // 2 MiB   (total 234 MiB)
    (void)ws_size; (void)in_sizes; (void)n_in; (void)out_size;

    // 1) cast all weights to bf16 (single launch)
    castw_all<<<dim3((N4_TOT + 255) / 256), 256, 0, stream>>>(
        Wqru, Wk, Wv, Wh, WqruB, WkB, WvB, WhB);

    // 2) layernorm(query) + bf16 casts of key/value (wave-per-row)
    prep_kernel<<<dim3(MROWS / 4), 256, 0, stream>>>(query, key_in, value, ln_w, ln_b, nq, kin, valb);

    // 3) kraw = key@Wk^T + bk
    gemm_bt<<<dim3(ZN / 128, MROWS / 128, 1), 256, 0, stream>>>(
        kin, WkB, 0LL, 0LL, EN, EpiRaw{kraw, bk});

    // 4) base = nq@Wqru^T + bqru -> qraw / u / r   (kin dead -> qraw region)
    gemm_bt<<<dim3(QRU_N / 128, MROWS / 128, 1), 256, 0, stream>>>(
        nq, WqruB, 0LL, 0LL, EN, EpiQru{qraw, ub, rb, bqru});

    // 5) merged l2norm for k and q
    l2norm_both<<<dim3(MROWS, 2), 256, 0, stream>>>(kraw, qraw, kb, qb, gamma, beta);

    // 6) v = silu(value@Wv^T + bv)  (b,c,e), then transpose to (b,e,c)
    gemm_bt<<<dim3(EN / 128, MROWS / 128, 1), 256, 0, stream>>>(
        valb, WvB, 0LL, 0LL, EN, EpiV{vbce, bv});
    transpose_bc<<<dim3(EN / 64, LN_ / 64, BN_), 256, 0, stream>>>(vbce, vT);

    // 7) attn = relu(q@k^T * scale + bias)^2   (batched over b)
    gemm_bt<<<dim3(LN_ / 128, LN_ / 128, BN_), 256, 0, stream>>>(
        qb, kb, (long long)LN_ * ZN, (long long)LN_ * ZN, ZN, EpiQK{attn, relpos});

    // 8) hr = (attn @ v) * r   (batched over b)
    gemm_bt<<<dim3(EN / 128, LN_ / 128, BN_), 256, 0, stream>>>(
        attn, vT, (long long)LN_ * LN_, (long long)EN * LN_, LN_, EpiH{hr, rb});

    // 9) out = query + u*((hr@Wh^T + bh) - query)
    gemm_bt<<<dim3(EN / 128, MROWS / 128, 1), 256, 0, stream>>>(
        hr, WhB, 0LL, 0LL, EN, EpiOut{out, query, ub, bh});
}

// Round 8
// 626.563 us; speedup vs baseline: 1.2278x; 1.0828x over previous
//
#include <hip/hip_runtime.h>
#include <cstdint>

// ---------------------------------------------------------------------------
// GatedCrossAttention  (E=1024, Z=256, L=2048, B=8)
// Round 8: round-7 engine + launch fusion.
//   pre    = prep(LN+casts) + weight-cast           (1 launch)
//   fused3 = qru-GEMM + k-GEMM + v-GEMM (all K=1024, block-partitioned)
//   post   = l2norm(k,q) + transpose(v)             (1 launch)
//   qk, h, out GEMMs unchanged (128^2 engine).
// Workspace re-laid for fused3 concurrency (lifetimes in comments below).
// ---------------------------------------------------------------------------

#define EN 1024
#define ZN 256
#define LN_ 2048
#define BN_ 8
#define MROWS (LN_ * BN_)          // 16384
#define QRU_N (2 * EN + ZN)        // 2304
#define LEN_SCALE 0.022097086912079608f  // 1/sqrt(2048)

typedef unsigned short u16;
typedef __bf16 bf16x8 __attribute__((ext_vector_type(8)));
typedef float f32x4 __attribute__((ext_vector_type(4)));

// ---- bf16 helpers ---------------------------------------------------------
__device__ __forceinline__ u16 f2bf(float f) {
    unsigned int u = __float_as_uint(f);
    u = (u + 0x7fff + ((u >> 16) & 1)) >> 16;
    return (u16)u;
}
__device__ __forceinline__ float bf2f(u16 s) {
    return __uint_as_float(((unsigned int)s) << 16);
}
__device__ __forceinline__ void store_bf16x4(u16* p, float a, float b, float c, float d) {
    union { u16 h[4]; uint2 v; } pk;
    pk.h[0] = f2bf(a); pk.h[1] = f2bf(b); pk.h[2] = f2bf(c); pk.h[3] = f2bf(d);
    *(uint2*)p = pk.v;
}

// ---- async global->LDS (16B/lane, wave-uniform LDS base + lane*16) --------
__device__ __forceinline__ void async_load16(const void* g, void* l) {
    __builtin_amdgcn_global_load_lds(
        (const __attribute__((address_space(1))) void*)g,
        (__attribute__((address_space(3))) void*)l,
        16, 0, 0);
}

// ===========================================================================
// Shared 128x128 BK=64 engine body (m97 structure + XOR LDS swizzle).
// Emitted as a macro so fused3 and gemm_bt share identical proven code.
// Defines/uses: As, Bs, lane, w, wm, wn, srow, scol, quad, l16, choff0/1, acc.
// ===========================================================================
#define GEMM_CORE(Ab, Bb, m0, n0, K)                                             \
    for (int k0 = 0; k0 < (K); k0 += 64) {                                       \
        __syncthreads();                                                         \
        _Pragma("unroll")                                                        \
        for (int t = 0; t < 4; ++t) {                                            \
            const int rbase = w * 32 + t * 8;                                    \
            async_load16((Ab) + ((m0) + rbase + srow) * (K) + (k0 + scol),       \
                         (void*)&As[rbase * 64]);                                \
            async_load16((Bb) + ((n0) + rbase + srow) * (K) + (k0 + scol),       \
                         (void*)&Bs[rbase * 64]);                                \
        }                                                                        \
        __builtin_amdgcn_s_waitcnt(0);                                           \
        __syncthreads();                                                         \
        _Pragma("unroll")                                                        \
        for (int h = 0; h < 2; ++h) {                                            \
            const int ch = h ? choff1 : choff0;                                  \
            bf16x8 af[4], bfv[4];                                                \
            _Pragma("unroll")                                                    \
            for (int mi = 0; mi < 4; ++mi)                                       \
                af[mi] = *(const bf16x8*)&As[(wm * 64 + mi * 16 + l16) * 64 + ch];\
            _Pragma("unroll")                                                    \
            for (int ni = 0; ni < 4; ++ni)                                       \
                bfv[ni] = *(const bf16x8*)&Bs[(wn * 64 + ni * 16 + l16) * 64 + ch];\
            _Pragma("unroll")                                                    \
            for (int mi = 0; mi < 4; ++mi)                                       \
                _Pragma("unroll")                                                \
                for (int ni = 0; ni < 4; ++ni)                                   \
                    acc[mi][ni] = __builtin_amdgcn_mfma_f32_16x16x32_bf16(       \
                        af[mi], bfv[ni], acc[mi][ni], 0, 0, 0);                  \
        }                                                                        \
    }

#define GEMM_PREAMBLE()                                                          \
    const int tid  = threadIdx.x;                                                \
    const int lane = tid & 63;                                                   \
    const int w    = tid >> 6;                                                   \
    const int wm   = w >> 1, wn = w & 1;                                         \
    const int srow = lane >> 3;                                                  \
    const int scol = ((lane & 7) ^ srow) * 8;                                    \
    const int quad = lane >> 4;                                                  \
    const int l16  = lane & 15;                                                  \
    const int choff0 = ((quad     ^ (l16 & 7)) * 8);                             \
    const int choff1 = (((4 + quad) ^ (l16 & 7)) * 8);                           \
    const f32x4 fzero = {0.f, 0.f, 0.f, 0.f};                                    \
    f32x4 acc[4][4];                                                             \
    _Pragma("unroll")                                                            \
    for (int i = 0; i < 4; ++i)                                                  \
        _Pragma("unroll")                                                        \
        for (int j = 0; j < 4; ++j) acc[i][j] = fzero;

// ===========================================================================
// fused3: qru (blocks 0..2303), k (2304..2559), v (2560..3583).  All K=1024.
// Per-segment T1 XCD swizzle (nwg = 2304 / 256 / 1024, all % 8 == 0).
// ===========================================================================
__global__ __launch_bounds__(256, 4)
void gemm_fused3(const u16* __restrict__ nq, const u16* __restrict__ kin,
                 const u16* __restrict__ valb,
                 const u16* __restrict__ Wqru, const u16* __restrict__ Wk,
                 const u16* __restrict__ Wv,
                 float* __restrict__ qraw, u16* __restrict__ ub, u16* __restrict__ rb,
                 const float* __restrict__ bqru,
                 float* __restrict__ kraw, const float* __restrict__ bk,
                 u16* __restrict__ vbce, const float* __restrict__ bv)
{
    __shared__ __align__(16) u16 As[128 * 64];
    __shared__ __align__(16) u16 Bs[128 * 64];

    const int id = blockIdx.x;
    int seg, local, gx, nwg;
    const u16 *A, *B;
    if (id < 2304)      { seg = 0; local = id;        gx = 18; nwg = 2304; A = nq;   B = Wqru; }
    else if (id < 2560) { seg = 1; local = id - 2304; gx = 2;  nwg = 256;  A = kin;  B = Wk;  }
    else                { seg = 2; local = id - 2560; gx = 8;  nwg = 1024; A = valb; B = Wv;  }
    const int swz = (local & 7) * (nwg >> 3) + (local >> 3);
    const long long m0 = (long long)(swz / gx) * 128;
    const long long n0 = (long long)(swz % gx) * 128;

    GEMM_PREAMBLE();
    GEMM_CORE(A, B, m0, n0, 1024);

    // epilogue: D[row][col], col = lane&15, row = quad*4 + reg  [m89/m91]
    if (seg == 0) {
#pragma unroll
        for (int mi = 0; mi < 4; ++mi)
#pragma unroll
            for (int ni = 0; ni < 4; ++ni)
#pragma unroll
                for (int r = 0; r < 4; ++r) {
                    int m = (int)m0 + wm * 64 + mi * 16 + quad * 4 + r;
                    int n = (int)n0 + wn * 64 + ni * 16 + l16;
                    float v = acc[mi][ni][r] + bqru[n];
                    if (n < ZN) {
                        qraw[(long long)m * ZN + n] = v;
                    } else if (n < ZN + EN) {
                        float s = 1.f / (1.f + __expf(-v));
                        ub[(long long)m * EN + (n - ZN)] = f2bf(s);
                    } else {
                        float s = v / (1.f + __expf(-v));
                        rb[(long long)m * EN + (n - ZN - EN)] = f2bf(s);
                    }
                }
    } else if (seg == 1) {
#pragma unroll
        for (int mi = 0; mi < 4; ++mi)
#pragma unroll
            for (int ni = 0; ni < 4; ++ni)
#pragma unroll
                for (int r = 0; r < 4; ++r) {
                    int m = (int)m0 + wm * 64 + mi * 16 + quad * 4 + r;
                    int n = (int)n0 + wn * 64 + ni * 16 + l16;
                    kraw[(long long)m * ZN + n] = acc[mi][ni][r] + bk[n];
                }
    } else {
#pragma unroll
        for (int mi = 0; mi < 4; ++mi)
#pragma unroll
            for (int ni = 0; ni < 4; ++ni)
#pragma unroll
                for (int r = 0; r < 4; ++r) {
                    int m = (int)m0 + wm * 64 + mi * 16 + quad * 4 + r;
                    int n = (int)n0 + wn * 64 + ni * 16 + l16;
                    float x = acc[mi][ni][r] + bv[n];
                    float s = x / (1.f + __expf(-x));
                    int b = m & 7, c = m >> 3;
                    vbce[((long long)b * LN_ + c) * EN + n] = f2bf(s);
                }
    }
}

// ===========================================================================
// standalone 128^2 engine (qk / h / out GEMMs)
// ===========================================================================
template <typename Epi>
__global__ __launch_bounds__(256, 4)
void gemm_bt(const u16* __restrict__ A, const u16* __restrict__ B,
             long long batchStrideA, long long batchStrideB, int K, Epi epi)
{
    __shared__ __align__(16) u16 As[128 * 64];
    __shared__ __align__(16) u16 Bs[128 * 64];

    const int bz   = blockIdx.z;
    const int gx   = gridDim.x;
    const int nwg  = gx * gridDim.y;
    const int orig = blockIdx.y * gx + blockIdx.x;
    const int swz  = ((nwg & 7) == 0) ? ((orig & 7) * (nwg >> 3) + (orig >> 3)) : orig;
    const long long m0 = (long long)(swz / gx) * 128;
    const long long n0 = (long long)(swz % gx) * 128;

    const u16* Ab = A + bz * batchStrideA;
    const u16* Bb = B + bz * batchStrideB;

    GEMM_PREAMBLE();
    GEMM_CORE(Ab, Bb, m0, n0, K);

#pragma unroll
    for (int mi = 0; mi < 4; ++mi)
#pragma unroll
        for (int ni = 0; ni < 4; ++ni)
#pragma unroll
            for (int r = 0; r < 4; ++r) {
                int m = (int)m0 + wm * 64 + mi * 16 + quad * 4 + r;
                int n = (int)n0 + wn * 64 + ni * 16 + l16;
                epi(bz, m, n, acc[mi][ni][r]);
            }
}

// ---- epilogue functors for the remaining GEMMs ------------------------------
struct EpiQK {             // attn = relu(qk*scale + bias)^2, bf16 (b, s, c)
    u16* attn; const float* relpos;
    __device__ void operator()(int bz, int m, int n, float v) const {
        float val = v * LEN_SCALE + relpos[2047 + n - m];
        float t = fmaxf(val, 0.f);
        attn[(long long)bz * LN_ * LN_ + (long long)m * LN_ + n] = f2bf(t * t);
    }
};
struct EpiH {              // hr = (attn@v) * r, bf16 rows (s*8+b)
    u16* hr; const u16* r;
    __device__ void operator()(int bz, int m, int n, float acc) const {
        long long idx = ((long long)m * BN_ + bz) * EN + n;
        hr[idx] = f2bf(acc * bf2f(r[idx]));
    }
};
struct EpiOut {            // out = query + u*((hr@Wh^T + bh) - query), fp32
    float* out; const float* query; const u16* u; const float* bh;
    __device__ void operator()(int, int m, int n, float acc) const {
        long long idx = (long long)m * EN + n;
        float qv = query[idx];
        float uu = bf2f(u[idx]);
        out[idx] = qv + uu * ((acc + bh[n]) - qv);
    }
};

// ---------------------------------------------------------------------------
// pre: blocks [0, MROWS/4) = prep (wave-per-row LN + casts);
//      blocks [MROWS/4, ..) = weight cast (grid-strided segments).
// ---------------------------------------------------------------------------
#define N4_QRU (QRU_N * EN / 4)            // 589824
#define N4_K   (ZN * EN / 4)               // 65536
#define N4_V   (EN * EN / 4)               // 262144
#define N4_H   (EN * EN / 4)               // 262144
#define N4_TOT (N4_QRU + N4_K + N4_V + N4_H)   // 1179648 = 4608 * 256
#define PREP_BLKS (MROWS / 4)              // 4096
#define CAST_BLKS (N4_TOT / 256)           // 4608

__global__ __launch_bounds__(256)
void pre_kernel(const float* __restrict__ query, const float* __restrict__ key_in,
                const float* __restrict__ value, const float* __restrict__ ln_w,
                const float* __restrict__ ln_b,
                u16* __restrict__ nq, u16* __restrict__ kin, u16* __restrict__ val,
                const float* __restrict__ Wqru, const float* __restrict__ Wk,
                const float* __restrict__ Wv,   const float* __restrict__ Wh,
                u16* __restrict__ dQru, u16* __restrict__ dK,
                u16* __restrict__ dV,   u16* __restrict__ dH)
{
    const int id = blockIdx.x;
    if (id < PREP_BLKS) {
        const int w = threadIdx.x >> 6, lane = threadIdx.x & 63;
        const int m = id * 4 + w;
        const long long rowb = (long long)m * EN;
        float4 q[4];
        float a1 = 0.f, a2 = 0.f;
#pragma unroll
        for (int p = 0; p < 4; ++p) {
            q[p] = *(const float4*)(query + rowb + p * 256 + lane * 4);
            a1 += q[p].x + q[p].y + q[p].z + q[p].w;
            a2 += q[p].x * q[p].x + q[p].y * q[p].y + q[p].z * q[p].z + q[p].w * q[p].w;
        }
#pragma unroll
        for (int o = 32; o; o >>= 1) { a1 += __shfl_down(a1, o, 64); a2 += __shfl_down(a2, o, 64); }
        const float S1 = __shfl(a1, 0, 64);
        const float S2 = __shfl(a2, 0, 64);
        const float mu = S1 * (1.f / EN);
        const float var = S2 * (1.f / EN) - mu * mu;
        const float rstd = rsqrtf(var + 1e-5f);
#pragma unroll
        for (int p = 0; p < 4; ++p) {
            const long long off = rowb + p * 256 + lane * 4;
            const int e = p * 256 + lane * 4;
            float4 wv = *(const float4*)(ln_w + e);
            float4 bvv = *(const float4*)(ln_b + e);
            store_bf16x4(nq + off,
                         (q[p].x - mu) * rstd * wv.x + bvv.x, (q[p].y - mu) * rstd * wv.y + bvv.y,
                         (q[p].z - mu) * rstd * wv.z + bvv.z, (q[p].w - mu) * rstd * wv.w + bvv.w);
            float4 kq = *(const float4*)(key_in + off);
            store_bf16x4(kin + off, kq.x, kq.y, kq.z, kq.w);
            float4 vq = *(const float4*)(value + off);
            store_bf16x4(val + off, vq.x, vq.y, vq.z, vq.w);
        }
    } else {
        int i = (id - PREP_BLKS) * 256 + threadIdx.x;
        const float* src; u16* dst; int j = i;
        if (j < N4_QRU)                { src = Wqru; dst = dQru; }
        else if ((j -= N4_QRU) < N4_K) { src = Wk;   dst = dK;   }
        else if ((j -= N4_K) < N4_V)   { src = Wv;   dst = dV;   }
        else { j -= N4_V;                src = Wh;   dst = dH;   }
        float4 x = ((const float4*)src)[j];
        store_bf16x4(dst + (long long)j * 4, x.x, x.y, x.z, x.w);
    }
}

// ---------------------------------------------------------------------------
// post: blocks [0, 2*MROWS) = l2norm (k then q); rest = transpose v->vT.
// ---------------------------------------------------------------------------
#define L2_BLKS (2 * MROWS)                 // 32768
#define TR_BLKS (BN_ * (LN_ / 64) * (EN / 64))  // 4096

__global__ __launch_bounds__(256)
void post_kernel(const float* __restrict__ kraw, const float* __restrict__ qraw,
                 u16* __restrict__ kb, u16* __restrict__ qb,
                 const float* __restrict__ gamma, const float* __restrict__ beta,
                 const u16* __restrict__ vbce, u16* __restrict__ vT)
{
    __shared__ u16 tile[64][65];           // also aliased as l2norm scratch
    const int id = blockIdx.x;
    if (id < L2_BLKS) {
        float* red = (float*)&tile[0][0];
        const int m = id & (MROWS - 1), z = threadIdx.x;
        const int which = id >> 14;            // 0 = k, 1 = q
        const float* raw = which ? qraw : kraw;
        u16* outp = which ? qb : kb;
        const float* g = gamma + (which ? 0 : ZN);
        const float* be = beta + (which ? 0 : ZN);
        const float x = raw[(long long)m * ZN + z];
        float ss = x * x;
#pragma unroll
        for (int o = 32; o; o >>= 1) ss += __shfl_down(ss, o, 64);
        if ((z & 63) == 0) red[z >> 6] = ss;
        __syncthreads();
        const float tot = red[0] + red[1] + red[2] + red[3];
        const float inv = 1.f / fmaxf(sqrtf(tot), 1e-5f);
        const float res = x * inv * (g[z] + 1.f) + be[z];
        const int b = m & 7, s = m >> 3;
        outp[((long long)b * LN_ + s) * ZN + z] = f2bf(res);
    } else {
        const int id2 = id - L2_BLKS;          // [0, 4096)
        const int b  = id2 >> 9;               // 512 tiles per batch
        const int rem = id2 & 511;
        const int e0 = (rem & 15) * 64, c0 = (rem >> 4) * 64;
        const int t  = threadIdx.x;
        const int rc = t >> 3;                 // 0..31
        const int ec = t & 7;                  // 0..7
        const u16* src = vbce + (long long)b * LN_ * EN;
        u16* dst = vT + (long long)b * EN * LN_;
#pragma unroll
        for (int i = 0; i < 64; i += 32) {
            union { uint4 v4; u16 h[8]; } ld;
            ld.v4 = *(const uint4*)(src + (long long)(c0 + rc + i) * EN + (e0 + ec * 8));
#pragma unroll
            for (int j = 0; j < 8; ++j) tile[rc + i][ec * 8 + j] = ld.h[j];
        }
        __syncthreads();
#pragma unroll
        for (int i = 0; i < 64; i += 32) {
            union { uint4 v4; u16 h[8]; } st;
#pragma unroll
            for (int j = 0; j < 8; ++j) st.h[j] = tile[ec * 8 + j][rc + i];
            *(uint4*)(dst + (long long)(e0 + rc + i) * LN_ + (c0 + ec * 8)) = st.v4;
        }
    }
}

// ---------------------------------------------------------------------------
extern "C" void kernel_launch(void* const* d_in, const int* in_sizes, int n_in,
                              void* d_out, int out_size, void* d_ws, size_t ws_size,
                              hipStream_t stream)
{
    const float* query  = (const float*)d_in[0];
    const float* key_in = (const float*)d_in[1];
    const float* value  = (const float*)d_in[2];
    const float* ln_w   = (const float*)d_in[3];
    const float* ln_b   = (const float*)d_in[4];
    const float* Wv     = (const float*)d_in[5];
    const float* bv     = (const float*)d_in[6];
    const float* Wk     = (const float*)d_in[7];
    const float* bk     = (const float*)d_in[8];
    const float* Wqru   = (const float*)d_in[9];
    const float* bqru   = (const float*)d_in[10];
    const float* Wh     = (const float*)d_in[11];
    const float* bh     = (const float*)d_in[12];
    const float* gamma  = (const float*)d_in[13];
    const float* beta   = (const float*)d_in[14];
    const float* relpos = (const float*)d_in[15];
    float* out = (float*)d_out;

    char* ws = (char*)d_ws;
    const size_t MB = 1ull << 20;
    // ---- lifetimes: S1 pre, S2 fused3, S3 post, S4 qk, S5 h, S6 out ----
    // S1->S2:  nq(0-32)  kin(32-64)  valb(64-96)
    // S2->S3:  vbce(96-128) qraw(128-144) kraw(144-160)
    // S2->S6:  ub(160-192)   S2->S5: rb(192-224)
    // S1->S2:  WqruB/WkB/WvB (224-231)   S1->S6: WhB(232-234)
    // S3->S5:  vT(0-32, over dead nq)
    // S3->S4:  qb(32-40) kb(40-48, over dead kin)
    // S4->S5:  attn(48-112, over dead kin/valb/vbce-lo)
    // S5->S6:  hr(112-144, over dead vbce-hi/qraw)
    u16*   nq    = (u16*)(ws + 0);
    u16*   kin   = (u16*)(ws + 32 * MB);
    u16*   valb  = (u16*)(ws + 64 * MB);
    u16*   vbce  = (u16*)(ws + 96 * MB);
    float* qraw  = (float*)(ws + 128 * MB);
    float* kraw  = (float*)(ws + 144 * MB);
    u16*   ub    = (u16*)(ws + 160 * MB);
    u16*   rb    = (u16*)(ws + 192 * MB);
    u16*   WqruB = (u16*)(ws + 224 * MB);   // 4.5 MiB
    u16*   WkB   = (u16*)(ws + 229 * MB);   // 0.5 MiB
    u16*   WvB   = (u16*)(ws + 230 * MB);   // 2 MiB
    u16*   WhB   = (u16*)(ws + 232 * MB);   // 2 MiB
    u16*   vT    = (u16*)(ws + 0);          // 32 MiB
    u16*   qb    = (u16*)(ws + 32 * MB);    // 8 MiB
    u16*   kb    = (u16*)(ws + 40 * MB);    // 8 MiB
    u16*   attn  = (u16*)(ws + 48 * MB);    // 64 MiB
    u16*   hr    = (u16*)(ws + 112 * MB);   // 32 MiB
    (void)ws_size; (void)in_sizes; (void)n_in; (void)out_size;

    // S1) prep + weight casts
    pre_kernel<<<dim3(PREP_BLKS + CAST_BLKS), 256, 0, stream>>>(
        query, key_in, value, ln_w, ln_b, nq, kin, valb,
        Wqru, Wk, Wv, Wh, WqruB, WkB, WvB, WhB);

    // S2) fused qru + k + v GEMMs (all K = 1024)
    gemm_fused3<<<dim3(2304 + 256 + 1024), 256, 0, stream>>>(
        nq, kin, valb, WqruB, WkB, WvB,
        qraw, ub, rb, bqru, kraw, bk, vbce, bv);

    // S3) l2norm (k and q) + transpose v -> vT
    post_kernel<<<dim3(L2_BLKS + TR_BLKS), 256, 0, stream>>>(
        kraw, qraw, kb, qb, gamma, beta, vbce, vT);

    // S4) attn = relu(q@k^T * scale + bias)^2   (batched over b, K=256)
    gemm_bt<<<dim3(LN_ / 128, LN_ / 128, BN_), 256, 0, stream>>>(
        qb, kb, (long long)LN_ * ZN, (long long)LN_ * ZN, ZN, EpiQK{attn, relpos});

    // S5) hr = (attn @ v) * r   (batched over b, K=2048)
    gemm_bt<<<dim3(EN / 128, LN_ / 128, BN_), 256, 0, stream>>>(
        attn, vT, (long long)LN_ * LN_, (long long)EN * LN_, LN_, EpiH{hr, rb});

    // S6) out = query + u*((hr@Wh^T + bh) - query)
    gemm_bt<<<dim3(EN / 128, MROWS / 128, 1), 256, 0, stream>>>(
        hr, WhB, 0LL, 0LL, EN, EpiOut{out, query, ub, bh});
}

// Round 9
// 608.796 us; speedup vs baseline: 1.2637x; 1.0292x over previous
//
#include <hip/hip_runtime.h>
#include <cstdint>

// ---------------------------------------------------------------------------
// GatedCrossAttention  (E=1024, Z=256, L=2048, B=8)
// Round 9: round-8 structure + wave-per-row vectorized l2norm in post.
//   pre    = prep(LN+casts) + weight-cast           (1 launch)
//   fused3 = qru-GEMM + k-GEMM + v-GEMM (all K=1024, block-partitioned)
//   post   = l2norm(k,q) [wave-per-row, float4] + transpose(v)
//   qk, h, out GEMMs unchanged (128^2 engine).
// ---------------------------------------------------------------------------

#define EN 1024
#define ZN 256
#define LN_ 2048
#define BN_ 8
#define MROWS (LN_ * BN_)          // 16384
#define QRU_N (2 * EN + ZN)        // 2304
#define LEN_SCALE 0.022097086912079608f  // 1/sqrt(2048)

typedef unsigned short u16;
typedef __bf16 bf16x8 __attribute__((ext_vector_type(8)));
typedef float f32x4 __attribute__((ext_vector_type(4)));

// ---- bf16 helpers ---------------------------------------------------------
__device__ __forceinline__ u16 f2bf(float f) {
    unsigned int u = __float_as_uint(f);
    u = (u + 0x7fff + ((u >> 16) & 1)) >> 16;
    return (u16)u;
}
__device__ __forceinline__ float bf2f(u16 s) {
    return __uint_as_float(((unsigned int)s) << 16);
}
__device__ __forceinline__ void store_bf16x4(u16* p, float a, float b, float c, float d) {
    union { u16 h[4]; uint2 v; } pk;
    pk.h[0] = f2bf(a); pk.h[1] = f2bf(b); pk.h[2] = f2bf(c); pk.h[3] = f2bf(d);
    *(uint2*)p = pk.v;
}

// ---- async global->LDS (16B/lane, wave-uniform LDS base + lane*16) --------
__device__ __forceinline__ void async_load16(const void* g, void* l) {
    __builtin_amdgcn_global_load_lds(
        (const __attribute__((address_space(1))) void*)g,
        (__attribute__((address_space(3))) void*)l,
        16, 0, 0);
}

// ===========================================================================
// Shared 128x128 BK=64 engine body (m97 structure + XOR LDS swizzle).
// ===========================================================================
#define GEMM_CORE(Ab, Bb, m0, n0, K)                                             \
    for (int k0 = 0; k0 < (K); k0 += 64) {                                       \
        __syncthreads();                                                         \
        _Pragma("unroll")                                                        \
        for (int t = 0; t < 4; ++t) {                                            \
            const int rbase = w * 32 + t * 8;                                    \
            async_load16((Ab) + ((m0) + rbase + srow) * (K) + (k0 + scol),       \
                         (void*)&As[rbase * 64]);                                \
            async_load16((Bb) + ((n0) + rbase + srow) * (K) + (k0 + scol),       \
                         (void*)&Bs[rbase * 64]);                                \
        }                                                                        \
        __builtin_amdgcn_s_waitcnt(0);                                           \
        __syncthreads();                                                         \
        _Pragma("unroll")                                                        \
        for (int h = 0; h < 2; ++h) {                                            \
            const int ch = h ? choff1 : choff0;                                  \
            bf16x8 af[4], bfv[4];                                                \
            _Pragma("unroll")                                                    \
            for (int mi = 0; mi < 4; ++mi)                                       \
                af[mi] = *(const bf16x8*)&As[(wm * 64 + mi * 16 + l16) * 64 + ch];\
            _Pragma("unroll")                                                    \
            for (int ni = 0; ni < 4; ++ni)                                       \
                bfv[ni] = *(const bf16x8*)&Bs[(wn * 64 + ni * 16 + l16) * 64 + ch];\
            _Pragma("unroll")                                                    \
            for (int mi = 0; mi < 4; ++mi)                                       \
                _Pragma("unroll")                                                \
                for (int ni = 0; ni < 4; ++ni)                                   \
                    acc[mi][ni] = __builtin_amdgcn_mfma_f32_16x16x32_bf16(       \
                        af[mi], bfv[ni], acc[mi][ni], 0, 0, 0);                  \
        }                                                                        \
    }

#define GEMM_PREAMBLE()                                                          \
    const int tid  = threadIdx.x;                                                \
    const int lane = tid & 63;                                                   \
    const int w    = tid >> 6;                                                   \
    const int wm   = w >> 1, wn = w & 1;                                         \
    const int srow = lane >> 3;                                                  \
    const int scol = ((lane & 7) ^ srow) * 8;                                    \
    const int quad = lane >> 4;                                                  \
    const int l16  = lane & 15;                                                  \
    const int choff0 = ((quad     ^ (l16 & 7)) * 8);                             \
    const int choff1 = (((4 + quad) ^ (l16 & 7)) * 8);                           \
    const f32x4 fzero = {0.f, 0.f, 0.f, 0.f};                                    \
    f32x4 acc[4][4];                                                             \
    _Pragma("unroll")                                                            \
    for (int i = 0; i < 4; ++i)                                                  \
        _Pragma("unroll")                                                        \
        for (int j = 0; j < 4; ++j) acc[i][j] = fzero;

// ===========================================================================
// fused3: qru (blocks 0..2303), k (2304..2559), v (2560..3583).  All K=1024.
// ===========================================================================
__global__ __launch_bounds__(256, 4)
void gemm_fused3(const u16* __restrict__ nq, const u16* __restrict__ kin,
                 const u16* __restrict__ valb,
                 const u16* __restrict__ Wqru, const u16* __restrict__ Wk,
                 const u16* __restrict__ Wv,
                 float* __restrict__ qraw, u16* __restrict__ ub, u16* __restrict__ rb,
                 const float* __restrict__ bqru,
                 float* __restrict__ kraw, const float* __restrict__ bk,
                 u16* __restrict__ vbce, const float* __restrict__ bv)
{
    __shared__ __align__(16) u16 As[128 * 64];
    __shared__ __align__(16) u16 Bs[128 * 64];

    const int id = blockIdx.x;
    int seg, local, gx, nwg;
    const u16 *A, *B;
    if (id < 2304)      { seg = 0; local = id;        gx = 18; nwg = 2304; A = nq;   B = Wqru; }
    else if (id < 2560) { seg = 1; local = id - 2304; gx = 2;  nwg = 256;  A = kin;  B = Wk;  }
    else                { seg = 2; local = id - 2560; gx = 8;  nwg = 1024; A = valb; B = Wv;  }
    const int swz = (local & 7) * (nwg >> 3) + (local >> 3);
    const long long m0 = (long long)(swz / gx) * 128;
    const long long n0 = (long long)(swz % gx) * 128;

    GEMM_PREAMBLE();
    GEMM_CORE(A, B, m0, n0, 1024);

    // epilogue: D[row][col], col = lane&15, row = quad*4 + reg  [m89/m91]
    if (seg == 0) {
#pragma unroll
        for (int mi = 0; mi < 4; ++mi)
#pragma unroll
            for (int ni = 0; ni < 4; ++ni)
#pragma unroll
                for (int r = 0; r < 4; ++r) {
                    int m = (int)m0 + wm * 64 + mi * 16 + quad * 4 + r;
                    int n = (int)n0 + wn * 64 + ni * 16 + l16;
                    float v = acc[mi][ni][r] + bqru[n];
                    if (n < ZN) {
                        qraw[(long long)m * ZN + n] = v;
                    } else if (n < ZN + EN) {
                        float s = 1.f / (1.f + __expf(-v));
                        ub[(long long)m * EN + (n - ZN)] = f2bf(s);
                    } else {
                        float s = v / (1.f + __expf(-v));
                        rb[(long long)m * EN + (n - ZN - EN)] = f2bf(s);
                    }
                }
    } else if (seg == 1) {
#pragma unroll
        for (int mi = 0; mi < 4; ++mi)
#pragma unroll
            for (int ni = 0; ni < 4; ++ni)
#pragma unroll
                for (int r = 0; r < 4; ++r) {
                    int m = (int)m0 + wm * 64 + mi * 16 + quad * 4 + r;
                    int n = (int)n0 + wn * 64 + ni * 16 + l16;
                    kraw[(long long)m * ZN + n] = acc[mi][ni][r] + bk[n];
                }
    } else {
#pragma unroll
        for (int mi = 0; mi < 4; ++mi)
#pragma unroll
            for (int ni = 0; ni < 4; ++ni)
#pragma unroll
                for (int r = 0; r < 4; ++r) {
                    int m = (int)m0 + wm * 64 + mi * 16 + quad * 4 + r;
                    int n = (int)n0 + wn * 64 + ni * 16 + l16;
                    float x = acc[mi][ni][r] + bv[n];
                    float s = x / (1.f + __expf(-x));
                    int b = m & 7, c = m >> 3;
                    vbce[((long long)b * LN_ + c) * EN + n] = f2bf(s);
                }
    }
}

// ===========================================================================
// standalone 128^2 engine (qk / h / out GEMMs)
// ===========================================================================
template <typename Epi>
__global__ __launch_bounds__(256, 4)
void gemm_bt(const u16* __restrict__ A, const u16* __restrict__ B,
             long long batchStrideA, long long batchStrideB, int K, Epi epi)
{
    __shared__ __align__(16) u16 As[128 * 64];
    __shared__ __align__(16) u16 Bs[128 * 64];

    const int bz   = blockIdx.z;
    const int gx   = gridDim.x;
    const int nwg  = gx * gridDim.y;
    const int orig = blockIdx.y * gx + blockIdx.x;
    const int swz  = ((nwg & 7) == 0) ? ((orig & 7) * (nwg >> 3) + (orig >> 3)) : orig;
    const long long m0 = (long long)(swz / gx) * 128;
    const long long n0 = (long long)(swz % gx) * 128;

    const u16* Ab = A + bz * batchStrideA;
    const u16* Bb = B + bz * batchStrideB;

    GEMM_PREAMBLE();
    GEMM_CORE(Ab, Bb, m0, n0, K);

#pragma unroll
    for (int mi = 0; mi < 4; ++mi)
#pragma unroll
        for (int ni = 0; ni < 4; ++ni)
#pragma unroll
            for (int r = 0; r < 4; ++r) {
                int m = (int)m0 + wm * 64 + mi * 16 + quad * 4 + r;
                int n = (int)n0 + wn * 64 + ni * 16 + l16;
                epi(bz, m, n, acc[mi][ni][r]);
            }
}

// ---- epilogue functors for the remaining GEMMs ------------------------------
struct EpiQK {             // attn = relu(qk*scale + bias)^2, bf16 (b, s, c)
    u16* attn; const float* relpos;
    __device__ void operator()(int bz, int m, int n, float v) const {
        float val = v * LEN_SCALE + relpos[2047 + n - m];
        float t = fmaxf(val, 0.f);
        attn[(long long)bz * LN_ * LN_ + (long long)m * LN_ + n] = f2bf(t * t);
    }
};
struct EpiH {              // hr = (attn@v) * r, bf16 rows (s*8+b)
    u16* hr; const u16* r;
    __device__ void operator()(int bz, int m, int n, float acc) const {
        long long idx = ((long long)m * BN_ + bz) * EN + n;
        hr[idx] = f2bf(acc * bf2f(r[idx]));
    }
};
struct EpiOut {            // out = query + u*((hr@Wh^T + bh) - query), fp32
    float* out; const float* query; const u16* u; const float* bh;
    __device__ void operator()(int, int m, int n, float acc) const {
        long long idx = (long long)m * EN + n;
        float qv = query[idx];
        float uu = bf2f(u[idx]);
        out[idx] = qv + uu * ((acc + bh[n]) - qv);
    }
};

// ---------------------------------------------------------------------------
// pre: blocks [0, MROWS/4) = prep (wave-per-row LN + casts);
//      blocks [MROWS/4, ..) = weight cast (grid-strided segments).
// ---------------------------------------------------------------------------
#define N4_QRU (QRU_N * EN / 4)            // 589824
#define N4_K   (ZN * EN / 4)               // 65536
#define N4_V   (EN * EN / 4)               // 262144
#define N4_H   (EN * EN / 4)               // 262144
#define N4_TOT (N4_QRU + N4_K + N4_V + N4_H)   // 1179648 = 4608 * 256
#define PREP_BLKS (MROWS / 4)              // 4096
#define CAST_BLKS (N4_TOT / 256)           // 4608

__global__ __launch_bounds__(256)
void pre_kernel(const float* __restrict__ query, const float* __restrict__ key_in,
                const float* __restrict__ value, const float* __restrict__ ln_w,
                const float* __restrict__ ln_b,
                u16* __restrict__ nq, u16* __restrict__ kin, u16* __restrict__ val,
                const float* __restrict__ Wqru, const float* __restrict__ Wk,
                const float* __restrict__ Wv,   const float* __restrict__ Wh,
                u16* __restrict__ dQru, u16* __restrict__ dK,
                u16* __restrict__ dV,   u16* __restrict__ dH)
{
    const int id = blockIdx.x;
    if (id < PREP_BLKS) {
        const int w = threadIdx.x >> 6, lane = threadIdx.x & 63;
        const int m = id * 4 + w;
        const long long rowb = (long long)m * EN;
        float4 q[4];
        float a1 = 0.f, a2 = 0.f;
#pragma unroll
        for (int p = 0; p < 4; ++p) {
            q[p] = *(const float4*)(query + rowb + p * 256 + lane * 4);
            a1 += q[p].x + q[p].y + q[p].z + q[p].w;
            a2 += q[p].x * q[p].x + q[p].y * q[p].y + q[p].z * q[p].z + q[p].w * q[p].w;
        }
#pragma unroll
        for (int o = 32; o; o >>= 1) { a1 += __shfl_down(a1, o, 64); a2 += __shfl_down(a2, o, 64); }
        const float S1 = __shfl(a1, 0, 64);
        const float S2 = __shfl(a2, 0, 64);
        const float mu = S1 * (1.f / EN);
        const float var = S2 * (1.f / EN) - mu * mu;
        const float rstd = rsqrtf(var + 1e-5f);
#pragma unroll
        for (int p = 0; p < 4; ++p) {
            const long long off = rowb + p * 256 + lane * 4;
            const int e = p * 256 + lane * 4;
            float4 wv = *(const float4*)(ln_w + e);
            float4 bvv = *(const float4*)(ln_b + e);
            store_bf16x4(nq + off,
                         (q[p].x - mu) * rstd * wv.x + bvv.x, (q[p].y - mu) * rstd * wv.y + bvv.y,
                         (q[p].z - mu) * rstd * wv.z + bvv.z, (q[p].w - mu) * rstd * wv.w + bvv.w);
            float4 kq = *(const float4*)(key_in + off);
            store_bf16x4(kin + off, kq.x, kq.y, kq.z, kq.w);
            float4 vq = *(const float4*)(value + off);
            store_bf16x4(val + off, vq.x, vq.y, vq.z, vq.w);
        }
    } else {
        int i = (id - PREP_BLKS) * 256 + threadIdx.x;
        const float* src; u16* dst; int j = i;
        if (j < N4_QRU)                { src = Wqru; dst = dQru; }
        else if ((j -= N4_QRU) < N4_K) { src = Wk;   dst = dK;   }
        else if ((j -= N4_K) < N4_V)   { src = Wv;   dst = dV;   }
        else { j -= N4_V;                src = Wh;   dst = dH;   }
        float4 x = ((const float4*)src)[j];
        store_bf16x4(dst + (long long)j * 4, x.x, x.y, x.z, x.w);
    }
}

// ---------------------------------------------------------------------------
// post: blocks [0, 8192) = l2norm wave-per-row (k rows then q rows);
//       blocks [8192, 12288) = transpose v->vT (64x64 LDS tiles, 16B both ways)
// ---------------------------------------------------------------------------
#define L2_BLKS (2 * MROWS / 4)             // 8192  (4 rows per block)
#define TR_BLKS (BN_ * (LN_ / 64) * (EN / 64))  // 4096

__global__ __launch_bounds__(256)
void post_kernel(const float* __restrict__ kraw, const float* __restrict__ qraw,
                 u16* __restrict__ kb, u16* __restrict__ qb,
                 const float* __restrict__ gamma, const float* __restrict__ beta,
                 const u16* __restrict__ vbce, u16* __restrict__ vT)
{
    __shared__ u16 tile[64][65];           // used only by transpose branch
    const int id = blockIdx.x;
    if (id < L2_BLKS) {
        // wave-per-row l2norm: row = id*4 + wave; Z=256 = 64 lanes x float4
        const int w = threadIdx.x >> 6, lane = threadIdx.x & 63;
        const int gm = id * 4 + w;             // 0..32767
        const int which = gm >> 14;            // 0 = k, 1 = q
        const int m = gm & (MROWS - 1);
        const float* raw = which ? qraw : kraw;
        u16* outp = which ? qb : kb;
        const float* g = gamma + (which ? 0 : ZN);
        const float* be = beta + (which ? 0 : ZN);

        float4 x = *(const float4*)(raw + (long long)m * ZN + lane * 4);
        float ss = x.x * x.x + x.y * x.y + x.z * x.z + x.w * x.w;
#pragma unroll
        for (int o = 32; o; o >>= 1) ss += __shfl_down(ss, o, 64);
        const float tot = __shfl(ss, 0, 64);
        const float inv = 1.f / fmaxf(sqrtf(tot), 1e-5f);
        float4 gv = *(const float4*)(g + lane * 4);
        float4 bv = *(const float4*)(be + lane * 4);
        const int b = m & 7, s = m >> 3;
        store_bf16x4(outp + ((long long)b * LN_ + s) * ZN + lane * 4,
                     x.x * inv * (gv.x + 1.f) + bv.x, x.y * inv * (gv.y + 1.f) + bv.y,
                     x.z * inv * (gv.z + 1.f) + bv.z, x.w * inv * (gv.w + 1.f) + bv.w);
    } else {
        const int id2 = id - L2_BLKS;          // [0, 4096)
        const int b  = id2 >> 9;               // 512 tiles per batch
        const int rem = id2 & 511;
        const int e0 = (rem & 15) * 64, c0 = (rem >> 4) * 64;
        const int t  = threadIdx.x;
        const int rc = t >> 3;                 // 0..31
        const int ec = t & 7;                  // 0..7
        const u16* src = vbce + (long long)b * LN_ * EN;
        u16* dst = vT + (long long)b * EN * LN_;
#pragma unroll
        for (int i = 0; i < 64; i += 32) {
            union { uint4 v4; u16 h[8]; } ld;
            ld.v4 = *(const uint4*)(src + (long long)(c0 + rc + i) * EN + (e0 + ec * 8));
#pragma unroll
            for (int j = 0; j < 8; ++j) tile[rc + i][ec * 8 + j] = ld.h[j];
        }
        __syncthreads();
#pragma unroll
        for (int i = 0; i < 64; i += 32) {
            union { uint4 v4; u16 h[8]; } st;
#pragma unroll
            for (int j = 0; j < 8; ++j) st.h[j] = tile[ec * 8 + j][rc + i];
            *(uint4*)(dst + (long long)(e0 + rc + i) * LN_ + (c0 + ec * 8)) = st.v4;
        }
    }
}

// ---------------------------------------------------------------------------
extern "C" void kernel_launch(void* const* d_in, const int* in_sizes, int n_in,
                              void* d_out, int out_size, void* d_ws, size_t ws_size,
                              hipStream_t stream)
{
    const float* query  = (const float*)d_in[0];
    const float* key_in = (const float*)d_in[1];
    const float* value  = (const float*)d_in[2];
    const float* ln_w   = (const float*)d_in[3];
    const float* ln_b   = (const float*)d_in[4];
    const float* Wv     = (const float*)d_in[5];
    const float* bv     = (const float*)d_in[6];
    const float* Wk     = (const float*)d_in[7];
    const float* bk     = (const float*)d_in[8];
    const float* Wqru   = (const float*)d_in[9];
    const float* bqru   = (const float*)d_in[10];
    const float* Wh     = (const float*)d_in[11];
    const float* bh     = (const float*)d_in[12];
    const float* gamma  = (const float*)d_in[13];
    const float* beta   = (const float*)d_in[14];
    const float* relpos = (const float*)d_in[15];
    float* out = (float*)d_out;

    char* ws = (char*)d_ws;
    const size_t MB = 1ull << 20;
    // ---- lifetimes: S1 pre, S2 fused3, S3 post, S4 qk, S5 h, S6 out ----
    // S1->S2:  nq(0-32)  kin(32-64)  valb(64-96)
    // S2->S3:  vbce(96-128) qraw(128-144) kraw(144-160)
    // S2->S6:  ub(160-192)   S2->S5: rb(192-224)
    // S1->S2:  WqruB/WkB/WvB (224-231)   S1->S6: WhB(232-234)
    // S3->S5:  vT(0-32, over dead nq)
    // S3->S4:  qb(32-40) kb(40-48, over dead kin)
    // S4->S5:  attn(48-112, over dead kin/valb/vbce-lo)
    // S5->S6:  hr(112-144, over dead vbce-hi/qraw)
    u16*   nq    = (u16*)(ws + 0);
    u16*   kin   = (u16*)(ws + 32 * MB);
    u16*   valb  = (u16*)(ws + 64 * MB);
    u16*   vbce  = (u16*)(ws + 96 * MB);
    float* qraw  = (float*)(ws + 128 * MB);
    float* kraw  = (float*)(ws + 144 * MB);
    u16*   ub    = (u16*)(ws + 160 * MB);
    u16*   rb    = (u16*)(ws + 192 * MB);
    u16*   WqruB = (u16*)(ws + 224 * MB);   // 4.5 MiB
    u16*   WkB   = (u16*)(ws + 229 * MB);   // 0.5 MiB
    u16*   WvB   = (u16*)(ws + 230 * MB);   // 2 MiB
    u16*   WhB   = (u16*)(ws + 232 * MB);   // 2 MiB
    u16*   vT    = (u16*)(ws + 0);          // 32 MiB
    u16*   qb    = (u16*)(ws + 32 * MB);    // 8 MiB
    u16*   kb    = (u16*)(ws + 40 * MB);    // 8 MiB
    u16*   attn  = (u16*)(ws + 48 * MB);    // 64 MiB
    u16*   hr    = (u16*)(ws + 112 * MB);   // 32 MiB
    (void)ws_size; (void)in_sizes; (void)n_in; (void)out_size;

    // S1) prep + weight casts
    pre_kernel<<<dim3(PREP_BLKS + CAST_BLKS), 256, 0, stream>>>(
        query, key_in, value, ln_w, ln_b, nq, kin, valb,
        Wqru, Wk, Wv, Wh, WqruB, WkB, WvB, WhB);

    // S2) fused qru + k + v GEMMs (all K = 1024)
    gemm_fused3<<<dim3(2304 + 256 + 1024), 256, 0, stream>>>(
        nq, kin, valb, WqruB, WkB, WvB,
        qraw, ub, rb, bqru, kraw, bk, vbce, bv);

    // S3) l2norm (k and q, wave-per-row) + transpose v -> vT
    post_kernel<<<dim3(L2_BLKS + TR_BLKS), 256, 0, stream>>>(
        kraw, qraw, kb, qb, gamma, beta, vbce, vT);

    // S4) attn = relu(q@k^T * scale + bias)^2   (batched over b, K=256)
    gemm_bt<<<dim3(LN_ / 128, LN_ / 128, BN_), 256, 0, stream>>>(
        qb, kb, (long long)LN_ * ZN, (long long)LN_ * ZN, ZN, EpiQK{attn, relpos});

    // S5) hr = (attn @ v) * r   (batched over b, K=2048)
    gemm_bt<<<dim3(EN / 128, LN_ / 128, BN_), 256, 0, stream>>>(
        attn, vT, (long long)LN_ * LN_, (long long)EN * LN_, LN_, EpiH{hr, rb});

    // S6) out = query + u*((hr@Wh^T + bh) - query)
    gemm_bt<<<dim3(EN / 128, MROWS / 128, 1), 256, 0, stream>>>(
        hr, WhB, 0LL, 0LL, EN, EpiOut{out, query, ub, bh});
}